// Round 1
// baseline (2945.842 us; speedup 1.0000x reference)
//
#include <hip/hip_runtime.h>
#include <cfloat>
#include <cmath>

#define TPB 256

// Problem constants
// B=2048, H=W=28, LATENT=128, MEM=8192, TOPK=10

__device__ __forceinline__ float wave_reduce_sum(float v) {
#pragma unroll
  for (int off = 32; off > 0; off >>= 1) v += __shfl_xor(v, off, 64);
  return v;
}

// ---------------------------------------------------------------------------
// Kernel 1: memory row inverse norms  invn[m] = 1/max(||mem[m]||, EPS)
// 4 rows per block (one wave each)
// ---------------------------------------------------------------------------
__global__ __launch_bounds__(256) void norm_kernel(
    const float* __restrict__ memg, float* __restrict__ invn) {
  const int wv = threadIdx.x >> 6, lane = threadIdx.x & 63;
  const int row = blockIdx.x * 4 + wv;
  const float* r = memg + (size_t)row * 128;
  float a = r[lane], b = r[lane + 64];
  float s = a * a + b * b;
  s = wave_reduce_sum(s);
  if (lane == 0) invn[row] = 1.f / fmaxf(sqrtf(s), 1e-12f);
}

// ---------------------------------------------------------------------------
// Kernel 2: encoder (conv3x3 1->32 relu, conv3x3 32->64 relu, spatial mean, FC)
// One block per image. h1 kept band-tiled in LDS; conv2 weights read as
// wave-uniform scalar loads (obase forced to SGPR via readfirstlane).
// S: spatial size, BH: band height (BH*S == 196 for both instantiations)
// ---------------------------------------------------------------------------
template <int S, int BH, bool CENTER>
__global__ __launch_bounds__(256) void encoder_kernel(
    const float* __restrict__ x, const float* __restrict__ w1,
    const float* __restrict__ b1, const float* __restrict__ w2,
    const float* __restrict__ b2, const float* __restrict__ fcw,
    const float* __restrict__ fcb, float* __restrict__ zout, int zoff) {
  constexpr int SP = S + 2;        // padded width
  constexpr int CR = BH + 2;       // band rows incl. halo
  constexpr int HSTR = CR * SP;    // per-channel stride in h1s
  constexpr int NPIX = BH * S;     // 196 for both instantiations

  __shared__ float xs[SP * SP];
  __shared__ float w1s[32 * 9];
  __shared__ float h1s[32 * HSTR];
  __shared__ float feat[64];

  const int b = blockIdx.x;
  const int t = threadIdx.x;
  const int lane = t & 63;
  const int wv = t >> 6;

  for (int e = t; e < SP * SP; e += TPB) xs[e] = 0.f;
  for (int e = t; e < 288; e += TPB) w1s[e] = w1[e];
  if (t < 64) feat[t] = 0.f;
  __syncthreads();
  const float* xb = x + (size_t)b * 784 + (CENTER ? (7 * 28 + 7) : 0);
  for (int e = t; e < S * S; e += TPB) {
    int i = e / S, j = e - i * S;
    xs[(i + 1) * SP + (j + 1)] = xb[i * 28 + j];
  }
  __syncthreads();

  for (int b0 = 0; b0 < S; b0 += BH) {
    // zero h1 band (provides zero-padding rows/cols)
    for (int e = t; e < 32 * HSTR; e += TPB) h1s[e] = 0.f;
    __syncthreads();
    // conv1 for input rows b0-1 .. b0+BH
    for (int e = t; e < 32 * CR * S; e += TPB) {
      int c = e / (CR * S);
      int rem = e - c * (CR * S);
      int lr = rem / S;
      int j = rem - lr * S;
      int gr = b0 - 1 + lr;
      if (gr >= 0 && gr < S) {
        float a = b1[c];
#pragma unroll
        for (int di = 0; di < 3; ++di)
#pragma unroll
          for (int dj = 0; dj < 3; ++dj)
            a += xs[(gr + di) * SP + (j + dj)] * w1s[c * 9 + di * 3 + dj];
        h1s[c * HSTR + lr * SP + (j + 1)] = fmaxf(a, 0.f);
      }
    }
    __syncthreads();
    // conv2 (o-blocked x4 per wave) + relu + spatial-mean partials
    int obase0 = __builtin_amdgcn_readfirstlane(wv * 16);
#pragma unroll 1
    for (int qq = 0; qq < 4; ++qq) {
      int obase = obase0 + qq * 4;
      float acc[4][4] = {};
#pragma unroll 1
      for (int c = 0; c < 32; ++c) {
        float wr[4][9];
#pragma unroll
        for (int oq = 0; oq < 4; ++oq)
#pragma unroll
          for (int j = 0; j < 9; ++j)
            wr[oq][j] = w2[(obase + oq) * 288 + c * 9 + j];  // uniform -> s_load
#pragma unroll
        for (int k = 0; k < 4; ++k) {
          int p = lane + 64 * k;
          int pp = p < NPIX ? p : NPIX - 1;  // clamp; garbage masked later
          int pr = pp / S, pc = pp - pr * S;
          const float* hp = &h1s[c * HSTR + pr * SP + pc];
          float hv[9];
#pragma unroll
          for (int di = 0; di < 3; ++di)
#pragma unroll
            for (int dj = 0; dj < 3; ++dj) hv[di * 3 + dj] = hp[di * SP + dj];
#pragma unroll
          for (int oq = 0; oq < 4; ++oq) {
            float s = acc[oq][k];
#pragma unroll
            for (int j = 0; j < 9; ++j) s += hv[j] * wr[oq][j];
            acc[oq][k] = s;
          }
        }
      }
#pragma unroll
      for (int oq = 0; oq < 4; ++oq) {
        float bb = b2[obase + oq];
        float s = 0.f;
#pragma unroll
        for (int k = 0; k < 4; ++k) {
          int p = lane + 64 * k;
          if (p < NPIX) s += fmaxf(acc[oq][k] + bb, 0.f);
        }
        s = wave_reduce_sum(s);
        if (lane == 0) feat[obase + oq] += s;  // wave owns these o's
      }
    }
    __syncthreads();
  }
  // FC: z[j] = mean(feat) @ fcw.T + fcb
  if (t < 64) {
    float s = 0.f;
#pragma unroll
    for (int i = 0; i < 64; ++i) s += feat[i] * fcw[t * 64 + i];
    zout[(size_t)b * 128 + zoff + t] = s * (1.f / (S * S)) + fcb[t];
  }
}

// ---------------------------------------------------------------------------
// Kernel 3: fused cosine-sim / top-10 / softmax / memory blend
// 8 z-rows per block; each thread owns 2 memory rows per tile; candidates
// above the running 10th-best are pushed to an LDS queue; 8 scanner threads
// maintain exact top-10 in registers.
// ---------------------------------------------------------------------------
__global__ __launch_bounds__(256) void match_kernel(
    const float* __restrict__ z, const float* __restrict__ memg,
    const float* __restrict__ invn, float* __restrict__ zmatch) {
  __shared__ __align__(16) float zs[8][128];
  __shared__ float qv[8][512];
  __shared__ int qi[8][512];
  __shared__ int qn[8];
  __shared__ float rowmin[8];
  __shared__ float topw[8][10];
  __shared__ int topidx[8][10];

  const int t = threadIdx.x;
  const int rowbase = blockIdx.x * 8;

  for (int e = t; e < 8 * 128; e += TPB) {
    int r = e >> 7, j = e & 127;
    zs[r][j] = z[(size_t)(rowbase + r) * 128 + j];
  }
  if (t < 8) { qn[t] = 0; rowmin[t] = -FLT_MAX; }
  __syncthreads();
  {  // normalize the 8 z rows in place (zn = z / max(||z||, EPS))
    int wv = t >> 6, lane = t & 63;
#pragma unroll
    for (int h = 0; h < 2; ++h) {
      int r = wv + h * 4;
      float a = zs[r][lane], b = zs[r][lane + 64];
      float s = wave_reduce_sum(a * a + b * b);
      float inv = 1.f / fmaxf(sqrtf(s), 1e-12f);
      zs[r][lane] = a * inv;
      zs[r][lane + 64] = b * inv;
    }
  }
  __syncthreads();

  float av[10];
  int ai[10];
#pragma unroll
  for (int i = 0; i < 10; ++i) { av[i] = -FLT_MAX; ai[i] = 0; }

  for (int mt = 0; mt < 16; ++mt) {
    int m0 = mt * 512 + t;
    float acc0[8] = {}, acc1[8] = {};
    const float4* mr0 = (const float4*)(memg + (size_t)m0 * 128);
    const float4* mr1 = (const float4*)(memg + (size_t)(m0 + 256) * 128);
#pragma unroll 4
    for (int jq = 0; jq < 32; ++jq) {
      float4 a0 = mr0[jq], a1 = mr1[jq];
#pragma unroll
      for (int r = 0; r < 8; ++r) {
        float4 zv = ((const float4*)zs[r])[jq];  // wave-uniform broadcast
        acc0[r] += a0.x * zv.x + a0.y * zv.y + a0.z * zv.z + a0.w * zv.w;
        acc1[r] += a1.x * zv.x + a1.y * zv.y + a1.z * zv.z + a1.w * zv.w;
      }
    }
    float i0 = invn[m0], i1 = invn[m0 + 256];
#pragma unroll
    for (int r = 0; r < 8; ++r) {
      float rm = rowmin[r];
      float v0 = acc0[r] * i0;
      if (v0 > rm) {
        int k = atomicAdd(&qn[r], 1);
        qv[r][k] = v0; qi[r][k] = m0;
      }
      float v1 = acc1[r] * i1;
      if (v1 > rm) {
        int k = atomicAdd(&qn[r], 1);
        qv[r][k] = v1; qi[r][k] = m0 + 256;
      }
    }
    __syncthreads();
    if (t < 8) {
      int n = qn[t];
      for (int k = 0; k < n; ++k) {
        float v = qv[t][k];
        int m = qi[t][k];
        if (v > av[9]) {
#pragma unroll
          for (int i = 0; i < 10; ++i) {
            if (v > av[i]) {
              float tv = av[i]; av[i] = v; v = tv;
              int ti = ai[i]; ai[i] = m; m = ti;
            }
          }
        }
      }
      qn[t] = 0;
      rowmin[t] = av[9];
    }
    __syncthreads();
  }

  if (t < 8) {
    float e_[10], s = 0.f;
#pragma unroll
    for (int k = 0; k < 10; ++k) { e_[k] = expf(av[k]); s += e_[k]; }
    float inv = 1.f / s;
#pragma unroll
    for (int k = 0; k < 10; ++k) { topw[t][k] = e_[k] * inv; topidx[t][k] = ai[k]; }
  }
  __syncthreads();
  for (int e = t; e < 8 * 128; e += TPB) {
    int r = e >> 7, d = e & 127;
    float o = 0.f;
#pragma unroll
    for (int k = 0; k < 10; ++k)
      o += topw[r][k] * memg[(size_t)topidx[r][k] * 128 + d];
    zmatch[(size_t)(rowbase + r) * 128 + d] = o;
  }
}

// ---------------------------------------------------------------------------
// Kernel 4: decoder FC GEMM  d0[2048][3136] = zmatch[2048][128] @ fcw.T + fcb
// 64-row x 128-col tiles; z tile in LDS, fcw streamed.
// ---------------------------------------------------------------------------
__global__ __launch_bounds__(256) void decfc_kernel(
    const float* __restrict__ zmatch, const float* __restrict__ fcw,
    const float* __restrict__ fcb, float* __restrict__ d0ws) {
  __shared__ __align__(16) float zt[64][128];
  const int t = threadIdx.x;
  const int c0 = blockIdx.x * 128;
  const int r0 = blockIdx.y * 64;
  {
    float4* zt4 = (float4*)&zt[0][0];
    const float4* zm4 = (const float4*)(zmatch + (size_t)r0 * 128);
    for (int e = t; e < 2048; e += TPB) zt4[e] = zm4[e];
  }
  __syncthreads();
  const int cg = (t & 31) * 4;
  const int rg = t >> 5;
  float acc[8][4] = {};
  for (int j = 0; j < 128; j += 4) {
    float4 wv[4];
#pragma unroll
    for (int c = 0; c < 4; ++c) {
      int col = c0 + cg + c;
      wv[c] = (col < 3136) ? *(const float4*)(fcw + (size_t)col * 128 + j)
                           : make_float4(0.f, 0.f, 0.f, 0.f);
    }
#pragma unroll
    for (int k = 0; k < 8; ++k) {
      float4 zv = *(const float4*)&zt[rg * 8 + k][j];
#pragma unroll
      for (int c = 0; c < 4; ++c)
        acc[k][c] += wv[c].x * zv.x + wv[c].y * zv.y + wv[c].z * zv.z + wv[c].w * zv.w;
    }
  }
  float bias[4];
#pragma unroll
  for (int c = 0; c < 4; ++c) {
    int col = c0 + cg + c;
    bias[c] = (col < 3136) ? fcb[col] : 0.f;
  }
#pragma unroll
  for (int k = 0; k < 8; ++k) {
    int row = r0 + rg * 8 + k;
#pragma unroll
    for (int c = 0; c < 4; ++c) {
      int col = c0 + cg + c;
      if (col < 3136) d0ws[(size_t)row * 3136 + col] = acc[k][c] + bias[c];
    }
  }
}

// ---------------------------------------------------------------------------
// Kernel 5: fused decoder. One block per image; all activations in LDS.
// deconv 4x4 s2 (64->32) relu, conv3x3 (32->16) relu, deconv 4x4 s2 (16->8)
// relu, conv3x3 (8->1). conv_transpose SAME/s2/k4 => pads (2,2) on the
// 2x-dilated input, kernel NOT flipped (HWIO).
// ---------------------------------------------------------------------------
__global__ __launch_bounds__(256) void decoder_kernel(
    const float* __restrict__ d0ws, const float* __restrict__ w1,
    const float* __restrict__ b1, const float* __restrict__ w2,
    const float* __restrict__ b2, const float* __restrict__ w3,
    const float* __restrict__ b3, const float* __restrict__ w4,
    const float* __restrict__ b4, float* __restrict__ out) {
  __shared__ __align__(16) float Wv[4608];  // staged weights (chunked)
  __shared__ __align__(16) float Bv[8192];  // d1 [32][16][16] then d3 [8][30][30]
  __shared__ __align__(16) float Uv[3136];  // d0 [64][7][7] then d2 [16][14][14]
  __shared__ float w4s[73];
  const int b = blockIdx.x;
  const int t = threadIdx.x;

  for (int e = t; e < 3136; e += TPB) Uv[e] = d0ws[(size_t)b * 3136 + e];
  for (int e = t; e < 8192; e += TPB) Bv[e] = 0.f;
  if (t < 72) w4s[t] = w4[t];
  if (t == 72) w4s[72] = b4[0];
  __syncthreads();

  // ---- deconv1: d0[64][7][7] -> d1[32][14][14], 8 chunks of 8 in-channels
  for (int cc = 0; cc < 8; ++cc) {
    for (int e = t; e < 4096; e += TPB) {
      int kh = e >> 10, kw = (e >> 8) & 3, c = (e >> 5) & 7, o = e & 31;
      Wv[e] = w1[(((kh * 4 + kw) * 64) + cc * 8 + c) * 32 + o];
    }
    __syncthreads();
    for (int e = t; e < 8 * 196; e += TPB) {  // 8 o-quads x 196 px
      int og = e / 196;
      int px = e - og * 196;
      int p = px / 14, q = px - p * 14;
      int o = og * 4;
      int idx = o * 256 + (p + 1) * 16 + (q + 1);
      float4 v;
      if (cc == 0) v = make_float4(b1[o], b1[o + 1], b1[o + 2], b1[o + 3]);
      else v = make_float4(Bv[idx], Bv[idx + 256], Bv[idx + 512], Bv[idx + 768]);
#pragma unroll
      for (int kh = 0; kh < 4; ++kh) {
        int u = p + kh - 2;
        if (u >= 0 && u <= 12 && !(u & 1)) {
          int ih = u >> 1;
#pragma unroll
          for (int kw = 0; kw < 4; ++kw) {
            int vq = q + kw - 2;
            if (vq >= 0 && vq <= 12 && !(vq & 1)) {
              int iw = vq >> 1;
#pragma unroll
              for (int c = 0; c < 8; ++c) {
                float uvv = Uv[(cc * 8 + c) * 49 + ih * 7 + iw];
                float4 wq = *(const float4*)&Wv[((kh * 4 + kw) * 8 + c) * 32 + o];
                v.x += uvv * wq.x; v.y += uvv * wq.y;
                v.z += uvv * wq.z; v.w += uvv * wq.w;
              }
            }
          }
        }
      }
      if (cc == 7) {
        v.x = fmaxf(v.x, 0.f); v.y = fmaxf(v.y, 0.f);
        v.z = fmaxf(v.z, 0.f); v.w = fmaxf(v.w, 0.f);
      }
      Bv[idx] = v.x; Bv[idx + 256] = v.y; Bv[idx + 512] = v.z; Bv[idx + 768] = v.w;
    }
    __syncthreads();
  }

  // ---- conv2: d1[32][14][14] -> d2[16][14][14] (weights transposed to [tap][c][o])
  for (int e = t; e < 4608; e += TPB) {
    int dt = e >> 9, c = (e >> 4) & 31, o = e & 15;
    Wv[e] = w2[(o * 32 + c) * 9 + dt];
  }
  __syncthreads();
  for (int e = t; e < 4 * 196; e += TPB) {
    int og = e / 196;
    int px = e - og * 196;
    int p = px / 14, q = px - p * 14;
    int o = og * 4;
    float4 v = make_float4(b2[o], b2[o + 1], b2[o + 2], b2[o + 3]);
#pragma unroll 1
    for (int c = 0; c < 32; ++c) {
      const float* bp = &Bv[c * 256 + p * 16 + q];
#pragma unroll
      for (int dt = 0; dt < 9; ++dt) {
        int di = dt / 3, dj = dt - di * 3;
        float bvv = bp[di * 16 + dj];
        float4 wq = *(const float4*)&Wv[(dt * 32 + c) * 16 + o];
        v.x += bvv * wq.x; v.y += bvv * wq.y; v.z += bvv * wq.z; v.w += bvv * wq.w;
      }
    }
    Uv[(o + 0) * 196 + px] = fmaxf(v.x, 0.f);
    Uv[(o + 1) * 196 + px] = fmaxf(v.y, 0.f);
    Uv[(o + 2) * 196 + px] = fmaxf(v.z, 0.f);
    Uv[(o + 3) * 196 + px] = fmaxf(v.w, 0.f);
  }
  __syncthreads();

  // ---- deconv2: d2[16][14][14] -> d3[8][28][28] (padded [8][30][30] in Bv)
  for (int e = t; e < 8192; e += TPB) Bv[e] = 0.f;
  for (int e = t; e < 2048; e += TPB) Wv[e] = w3[e];
  __syncthreads();
  for (int e = t; e < 2 * 784; e += TPB) {
    int og = e / 784;
    int px = e - og * 784;
    int p = px / 28, q = px - p * 28;
    int o = og * 4;
    float4 v = make_float4(b3[o], b3[o + 1], b3[o + 2], b3[o + 3]);
#pragma unroll
    for (int kh = 0; kh < 4; ++kh) {
      int u = p + kh - 2;
      if (u >= 0 && u <= 26 && !(u & 1)) {
        int ih = u >> 1;
#pragma unroll
        for (int kw = 0; kw < 4; ++kw) {
          int vq = q + kw - 2;
          if (vq >= 0 && vq <= 26 && !(vq & 1)) {
            int iw = vq >> 1;
#pragma unroll
            for (int c = 0; c < 16; ++c) {
              float uvv = Uv[c * 196 + ih * 14 + iw];
              float4 wq = *(const float4*)&Wv[((kh * 4 + kw) * 16 + c) * 8 + o];
              v.x += uvv * wq.x; v.y += uvv * wq.y;
              v.z += uvv * wq.z; v.w += uvv * wq.w;
            }
          }
        }
      }
    }
    int idx = o * 900 + (p + 1) * 30 + (q + 1);
    Bv[idx] = fmaxf(v.x, 0.f);
    Bv[idx + 900] = fmaxf(v.y, 0.f);
    Bv[idx + 1800] = fmaxf(v.z, 0.f);
    Bv[idx + 2700] = fmaxf(v.w, 0.f);
  }
  __syncthreads();

  // ---- final conv: d3[8][28][28] -> out[1][28][28], no relu
  for (int e = t; e < 784; e += TPB) {
    int p = e / 28, q = e - p * 28;
    float a = w4s[72];
#pragma unroll
    for (int c = 0; c < 8; ++c) {
      const float* bp = &Bv[c * 900 + p * 30 + q];
      const float* wp = &w4s[c * 9];
#pragma unroll
      for (int di = 0; di < 3; ++di)
#pragma unroll
        for (int dj = 0; dj < 3; ++dj) a += bp[di * 30 + dj] * wp[di * 3 + dj];
    }
    out[(size_t)b * 784 + e] = a;
  }
}

// ---------------------------------------------------------------------------
extern "C" void kernel_launch(void* const* d_in, const int* in_sizes, int n_in,
                              void* d_out, int out_size, void* d_ws,
                              size_t ws_size, hipStream_t stream) {
  const float* x      = (const float*)d_in[0];
  const float* ce_w1  = (const float*)d_in[1];
  const float* ce_b1  = (const float*)d_in[2];
  const float* ce_w2  = (const float*)d_in[3];
  const float* ce_b2  = (const float*)d_in[4];
  const float* ce_fcw = (const float*)d_in[5];
  const float* ce_fcb = (const float*)d_in[6];
  const float* ge_w1  = (const float*)d_in[7];
  const float* ge_b1  = (const float*)d_in[8];
  const float* ge_w2  = (const float*)d_in[9];
  const float* ge_b2  = (const float*)d_in[10];
  const float* ge_fcw = (const float*)d_in[11];
  const float* ge_fcb = (const float*)d_in[12];
  const float* memg   = (const float*)d_in[13];
  const float* dfcw   = (const float*)d_in[14];
  const float* dfcb   = (const float*)d_in[15];
  const float* d_w1   = (const float*)d_in[16];
  const float* d_b1   = (const float*)d_in[17];
  const float* d_w2   = (const float*)d_in[18];
  const float* d_b2   = (const float*)d_in[19];
  const float* d_w3   = (const float*)d_in[20];
  const float* d_b3   = (const float*)d_in[21];
  const float* d_w4   = (const float*)d_in[22];
  const float* d_b4   = (const float*)d_in[23];
  float* outp = (float*)d_out;

  // ws layout (floats): z[2048*128] | zmatch[2048*128] | invn[8192] | d0[2048*3136]
  // total ~27.8 MB
  float* ws     = (float*)d_ws;
  float* z      = ws;
  float* zmatch = ws + 262144;
  float* invn   = ws + 524288;
  float* d0ws   = ws + 532480;

  norm_kernel<<<2048, TPB, 0, stream>>>(memg, invn);
  encoder_kernel<14, 14, true><<<2048, TPB, 0, stream>>>(
      x, ce_w1, ce_b1, ce_w2, ce_b2, ce_fcw, ce_fcb, z, 0);
  encoder_kernel<28, 7, false><<<2048, TPB, 0, stream>>>(
      x, ge_w1, ge_b1, ge_w2, ge_b2, ge_fcw, ge_fcb, z, 64);
  match_kernel<<<256, TPB, 0, stream>>>(z, memg, invn, zmatch);
  decfc_kernel<<<dim3(25, 32), TPB, 0, stream>>>(zmatch, dfcw, dfcb, d0ws);
  decoder_kernel<<<2048, TPB, 0, stream>>>(d0ws, d_w1, d_b1, d_w2, d_b2, d_w3,
                                           d_b3, d_w4, d_b4, outp);
}

// Round 2
// 1929.828 us; speedup vs baseline: 1.5265x; 1.5265x over previous
//
#include <hip/hip_runtime.h>
#include <cfloat>
#include <cmath>

#define TPB 256

// Problem constants
// B=2048, H=W=28, LATENT=128, MEM=8192, TOPK=10

__device__ __forceinline__ float wave_reduce_sum(float v) {
#pragma unroll
  for (int off = 32; off > 0; off >>= 1) v += __shfl_xor(v, off, 64);
  return v;
}

// ---------------------------------------------------------------------------
// Kernel 1: memory row inverse norms  invn[m] = 1/max(||mem[m]||, EPS)
// ---------------------------------------------------------------------------
__global__ __launch_bounds__(256) void norm_kernel(
    const float* __restrict__ memg, float* __restrict__ invn) {
  const int wv = threadIdx.x >> 6, lane = threadIdx.x & 63;
  const int row = blockIdx.x * 4 + wv;
  const float* r = memg + (size_t)row * 128;
  float a = r[lane], b = r[lane + 64];
  float s = a * a + b * b;
  s = wave_reduce_sum(s);
  if (lane == 0) invn[row] = 1.f / fmaxf(sqrtf(s), 1e-12f);
}

// ---------------------------------------------------------------------------
// Kernel 2: encoder. conv2 lanes remapped to (row,col)=(lane/LW, lane&(LW-1))
// so each wave LDS read spans aligned rows -> max 2-way bank aliasing (free).
// ---------------------------------------------------------------------------
template <int S, int BH, bool CENTER>
__global__ __launch_bounds__(256) void encoder_kernel(
    const float* __restrict__ x, const float* __restrict__ w1,
    const float* __restrict__ b1, const float* __restrict__ w2,
    const float* __restrict__ b2, const float* __restrict__ fcw,
    const float* __restrict__ fcb, float* __restrict__ zout, int zoff) {
  constexpr int SP = S + 2;        // padded width
  constexpr int CR = BH + 2;       // band rows incl. halo
  constexpr int HSTR = CR * SP;    // per-channel stride in h1s
  constexpr int LW = (S >= 16) ? 32 : 16;  // lane-row width
  constexpr int RPK = 64 / LW;             // rows per k-iter

  __shared__ float xs[SP * SP];
  __shared__ float w1s[32 * 9];
  __shared__ float h1s[32 * HSTR];
  __shared__ float feat[64];

  const int b = blockIdx.x;
  const int t = threadIdx.x;
  const int lane = t & 63;
  const int wv = t >> 6;

  for (int e = t; e < SP * SP; e += TPB) xs[e] = 0.f;
  for (int e = t; e < 288; e += TPB) w1s[e] = w1[e];
  if (t < 64) feat[t] = 0.f;
  __syncthreads();
  const float* xb = x + (size_t)b * 784 + (CENTER ? (7 * 28 + 7) : 0);
  for (int e = t; e < S * S; e += TPB) {
    int i = e / S, j = e - i * S;
    xs[(i + 1) * SP + (j + 1)] = xb[i * 28 + j];
  }
  __syncthreads();

  const int pc = lane & (LW - 1);
  const int prl = lane / LW;
  const int cpc = pc < S ? pc : S - 1;

  for (int b0 = 0; b0 < S; b0 += BH) {
    for (int e = t; e < 32 * HSTR; e += TPB) h1s[e] = 0.f;
    __syncthreads();
    // conv1 for input rows b0-1 .. b0+BH
    for (int e = t; e < 32 * CR * S; e += TPB) {
      int c = e / (CR * S);
      int rem = e - c * (CR * S);
      int lr = rem / S;
      int j = rem - lr * S;
      int gr = b0 - 1 + lr;
      if (gr >= 0 && gr < S) {
        float a = b1[c];
#pragma unroll
        for (int di = 0; di < 3; ++di)
#pragma unroll
          for (int dj = 0; dj < 3; ++dj)
            a += xs[(gr + di) * SP + (j + dj)] * w1s[c * 9 + di * 3 + dj];
        h1s[c * HSTR + lr * SP + (j + 1)] = fmaxf(a, 0.f);
      }
    }
    __syncthreads();
    // conv2 (o-blocked x4 per wave) + relu + spatial-mean partials
    int obase0 = __builtin_amdgcn_readfirstlane(wv * 16);
#pragma unroll 1
    for (int qq = 0; qq < 4; ++qq) {
      int obase = obase0 + qq * 4;
      float acc[4][4] = {};
#pragma unroll 1
      for (int c = 0; c < 32; ++c) {
        float wr[4][9];
#pragma unroll
        for (int oq = 0; oq < 4; ++oq)
#pragma unroll
          for (int j = 0; j < 9; ++j)
            wr[oq][j] = w2[(obase + oq) * 288 + c * 9 + j];  // uniform -> s_load
#pragma unroll
        for (int k = 0; k < 4; ++k) {
          int row = k * RPK + prl;
          int crow = row < BH ? row : BH - 1;
          const float* hp = &h1s[c * HSTR + crow * SP + cpc];
          float hv[9];
#pragma unroll
          for (int di = 0; di < 3; ++di)
#pragma unroll
            for (int dj = 0; dj < 3; ++dj) hv[di * 3 + dj] = hp[di * SP + dj];
#pragma unroll
          for (int oq = 0; oq < 4; ++oq) {
            float s = acc[oq][k];
#pragma unroll
            for (int j = 0; j < 9; ++j) s += hv[j] * wr[oq][j];
            acc[oq][k] = s;
          }
        }
      }
#pragma unroll
      for (int oq = 0; oq < 4; ++oq) {
        float bb = b2[obase + oq];
        float s = 0.f;
#pragma unroll
        for (int k = 0; k < 4; ++k) {
          int row = k * RPK + prl;
          if (pc < S && row < BH) s += fmaxf(acc[oq][k] + bb, 0.f);
        }
        s = wave_reduce_sum(s);
        if (lane == 0) feat[obase + oq] += s;  // wave owns these o's
      }
    }
    __syncthreads();
  }
  // FC: z[j] = mean(feat) @ fcw.T + fcb
  if (t < 64) {
    float s = 0.f;
#pragma unroll
    for (int i = 0; i < 64; ++i) s += feat[i] * fcw[t * 64 + i];
    zout[(size_t)b * 128 + zoff + t] = s * (1.f / (S * S)) + fcb[t];
  }
}

// ---------------------------------------------------------------------------
// Kernel 3: fused cosine-sim / top-10 / softmax / memory blend (unchanged)
// ---------------------------------------------------------------------------
__global__ __launch_bounds__(256) void match_kernel(
    const float* __restrict__ z, const float* __restrict__ memg,
    const float* __restrict__ invn, float* __restrict__ zmatch) {
  __shared__ __align__(16) float zs[8][128];
  __shared__ float qv[8][512];
  __shared__ int qi[8][512];
  __shared__ int qn[8];
  __shared__ float rowmin[8];
  __shared__ float topw[8][10];
  __shared__ int topidx[8][10];

  const int t = threadIdx.x;
  const int rowbase = blockIdx.x * 8;

  for (int e = t; e < 8 * 128; e += TPB) {
    int r = e >> 7, j = e & 127;
    zs[r][j] = z[(size_t)(rowbase + r) * 128 + j];
  }
  if (t < 8) { qn[t] = 0; rowmin[t] = -FLT_MAX; }
  __syncthreads();
  {
    int wv = t >> 6, lane = t & 63;
#pragma unroll
    for (int h = 0; h < 2; ++h) {
      int r = wv + h * 4;
      float a = zs[r][lane], b = zs[r][lane + 64];
      float s = wave_reduce_sum(a * a + b * b);
      float inv = 1.f / fmaxf(sqrtf(s), 1e-12f);
      zs[r][lane] = a * inv;
      zs[r][lane + 64] = b * inv;
    }
  }
  __syncthreads();

  float av[10];
  int ai[10];
#pragma unroll
  for (int i = 0; i < 10; ++i) { av[i] = -FLT_MAX; ai[i] = 0; }

  for (int mt = 0; mt < 16; ++mt) {
    int m0 = mt * 512 + t;
    float acc0[8] = {}, acc1[8] = {};
    const float4* mr0 = (const float4*)(memg + (size_t)m0 * 128);
    const float4* mr1 = (const float4*)(memg + (size_t)(m0 + 256) * 128);
#pragma unroll 4
    for (int jq = 0; jq < 32; ++jq) {
      float4 a0 = mr0[jq], a1 = mr1[jq];
#pragma unroll
      for (int r = 0; r < 8; ++r) {
        float4 zv = ((const float4*)zs[r])[jq];
        acc0[r] += a0.x * zv.x + a0.y * zv.y + a0.z * zv.z + a0.w * zv.w;
        acc1[r] += a1.x * zv.x + a1.y * zv.y + a1.z * zv.z + a1.w * zv.w;
      }
    }
    float i0 = invn[m0], i1 = invn[m0 + 256];
#pragma unroll
    for (int r = 0; r < 8; ++r) {
      float rm = rowmin[r];
      float v0 = acc0[r] * i0;
      if (v0 > rm) {
        int k = atomicAdd(&qn[r], 1);
        qv[r][k] = v0; qi[r][k] = m0;
      }
      float v1 = acc1[r] * i1;
      if (v1 > rm) {
        int k = atomicAdd(&qn[r], 1);
        qv[r][k] = v1; qi[r][k] = m0 + 256;
      }
    }
    __syncthreads();
    if (t < 8) {
      int n = qn[t];
      for (int k = 0; k < n; ++k) {
        float v = qv[t][k];
        int m = qi[t][k];
        if (v > av[9]) {
#pragma unroll
          for (int i = 0; i < 10; ++i) {
            if (v > av[i]) {
              float tv = av[i]; av[i] = v; v = tv;
              int ti = ai[i]; ai[i] = m; m = ti;
            }
          }
        }
      }
      qn[t] = 0;
      rowmin[t] = av[9];
    }
    __syncthreads();
  }

  if (t < 8) {
    float e_[10], s = 0.f;
#pragma unroll
    for (int k = 0; k < 10; ++k) { e_[k] = expf(av[k]); s += e_[k]; }
    float inv = 1.f / s;
#pragma unroll
    for (int k = 0; k < 10; ++k) { topw[t][k] = e_[k] * inv; topidx[t][k] = ai[k]; }
  }
  __syncthreads();
  for (int e = t; e < 8 * 128; e += TPB) {
    int r = e >> 7, d = e & 127;
    float o = 0.f;
#pragma unroll
    for (int k = 0; k < 10; ++k)
      o += topw[r][k] * memg[(size_t)topidx[r][k] * 128 + d];
    zmatch[(size_t)(rowbase + r) * 128 + d] = o;
  }
}

// ---------------------------------------------------------------------------
// Kernel 4: decoder FC GEMM (unchanged)
// ---------------------------------------------------------------------------
__global__ __launch_bounds__(256) void decfc_kernel(
    const float* __restrict__ zmatch, const float* __restrict__ fcw,
    const float* __restrict__ fcb, float* __restrict__ d0ws) {
  __shared__ __align__(16) float zt[64][128];
  const int t = threadIdx.x;
  const int c0 = blockIdx.x * 128;
  const int r0 = blockIdx.y * 64;
  {
    float4* zt4 = (float4*)&zt[0][0];
    const float4* zm4 = (const float4*)(zmatch + (size_t)r0 * 128);
    for (int e = t; e < 2048; e += TPB) zt4[e] = zm4[e];
  }
  __syncthreads();
  const int cg = (t & 31) * 4;
  const int rg = t >> 5;
  float acc[8][4] = {};
  for (int j = 0; j < 128; j += 4) {
    float4 wv[4];
#pragma unroll
    for (int c = 0; c < 4; ++c) {
      int col = c0 + cg + c;
      wv[c] = (col < 3136) ? *(const float4*)(fcw + (size_t)col * 128 + j)
                           : make_float4(0.f, 0.f, 0.f, 0.f);
    }
#pragma unroll
    for (int k = 0; k < 8; ++k) {
      float4 zv = *(const float4*)&zt[rg * 8 + k][j];
#pragma unroll
      for (int c = 0; c < 4; ++c)
        acc[k][c] += wv[c].x * zv.x + wv[c].y * zv.y + wv[c].z * zv.z + wv[c].w * zv.w;
    }
  }
  float bias[4];
#pragma unroll
  for (int c = 0; c < 4; ++c) {
    int col = c0 + cg + c;
    bias[c] = (col < 3136) ? fcb[col] : 0.f;
  }
#pragma unroll
  for (int k = 0; k < 8; ++k) {
    int row = r0 + rg * 8 + k;
#pragma unroll
    for (int c = 0; c < 4; ++c) {
      int col = c0 + cg + c;
      if (col < 3136) d0ws[(size_t)row * 3136 + col] = acc[k][c] + bias[c];
    }
  }
}

// ---------------------------------------------------------------------------
// Kernel 5: fused decoder v2. One block per image, 4 waves.
// Deconvs phase-decomposed: wave = output parity phase (readfirstlane ->
// wave-uniform weight addressing -> s_load, zero branches, exactly 2x2 taps).
// Register accumulators; 5 syncs; LDS 44.3 KB -> 3 blocks/CU.
// ---------------------------------------------------------------------------
__global__ __launch_bounds__(256) void decoder_kernel(
    const float* __restrict__ d0g, const float* __restrict__ w1,
    const float* __restrict__ b1, const float* __restrict__ w2,
    const float* __restrict__ b2, const float* __restrict__ w3,
    const float* __restrict__ b3, const float* __restrict__ w4,
    const float* __restrict__ b4, float* __restrict__ out) {
  __shared__ float Buf1[3136];  // d0 [64][7][7], later d2 [16][196]
  __shared__ float Buf2[8192];  // d1 [32][16][16] padded, later d3 [8][30][30]

  const int b = blockIdx.x;
  const int t = threadIdx.x;
  const int lane = t & 63;
  const int ph = __builtin_amdgcn_readfirstlane(t >> 6);  // wave = phase
  const int pa = ph >> 1, pb = ph & 1;

  for (int e = t; e < 3136; e += TPB) Buf1[e] = d0g[(size_t)b * 3136 + e];
  for (int e = t; e < 8192; e += TPB) Buf2[e] = 0.f;
  __syncthreads();

  // ---- deconv1: d0[64][7][7] -> d1[32][14][14]; wave handles phase (pa,pb)
  {
    const int i = lane / 7, j = lane % 7;  // lanes >= 49 masked on write
    const int p = 2 * i + pa, q = 2 * j + pb;
    int ih[2], iw[2];
    float mh[2], mw[2];
#pragma unroll
    for (int s = 0; s < 2; ++s) {
      int v = i + pa + s - 1;
      mh[s] = (v >= 0 && v <= 6) ? 1.f : 0.f;
      ih[s] = v < 0 ? 0 : (v > 6 ? 6 : v);
      int u = j + pb + s - 1;
      mw[s] = (u >= 0 && u <= 6) ? 1.f : 0.f;
      iw[s] = u < 0 ? 0 : (u > 6 ? 6 : u);
    }
    const float m00 = mh[0] * mw[0], m01 = mh[0] * mw[1];
    const float m10 = mh[1] * mw[0], m11 = mh[1] * mw[1];
    const int tb = pa * 4 + pb;  // kh = pa+2s, kw = pb+2t
    const float* wA = w1 + (size_t)tb * 2048;
    const float* wB = w1 + (size_t)(tb + 2) * 2048;
    const float* wC = w1 + (size_t)(tb + 8) * 2048;
    const float* wD = w1 + (size_t)(tb + 10) * 2048;
#pragma unroll 1
    for (int half = 0; half < 2; ++half) {
      const int o0 = half * 16;
      float acc[16];
#pragma unroll
      for (int oo = 0; oo < 16; ++oo) acc[oo] = b1[o0 + oo];
#pragma unroll 2
      for (int c = 0; c < 64; ++c) {
        const float a00 = Buf1[c * 49 + ih[0] * 7 + iw[0]] * m00;
        const float a01 = Buf1[c * 49 + ih[0] * 7 + iw[1]] * m01;
        const float a10 = Buf1[c * 49 + ih[1] * 7 + iw[0]] * m10;
        const float a11 = Buf1[c * 49 + ih[1] * 7 + iw[1]] * m11;
        const int wb = c * 32 + o0;
#pragma unroll
        for (int oo = 0; oo < 16; ++oo)
          acc[oo] += a00 * wA[wb + oo] + a01 * wB[wb + oo] +
                     a10 * wC[wb + oo] + a11 * wD[wb + oo];
      }
      if (lane < 49) {
        const int widx = (p + 1) * 16 + (q + 1);
#pragma unroll
        for (int oo = 0; oo < 16; ++oo)
          Buf2[(o0 + oo) * 256 + widx] = fmaxf(acc[oo], 0.f);
      }
    }
  }
  __syncthreads();

  // ---- conv2: d1[32][14][14] -> d2[16][196]; wave = o-quad, lanes (prl,pc)
  {
    const int oq = __builtin_amdgcn_readfirstlane((t >> 6) * 4);
    const int pc2 = lane & 15, prl = lane >> 4;
    const int cpc = pc2 < 14 ? pc2 : 13;
    float acc[4][4] = {};  // [oq][k]
#pragma unroll 1
    for (int c = 0; c < 32; ++c) {
      float wr[4][9];
#pragma unroll
      for (int oo = 0; oo < 4; ++oo)
#pragma unroll
        for (int u = 0; u < 9; ++u)
          wr[oo][u] = w2[((oq + oo) * 32 + c) * 9 + u];  // uniform -> s_load
#pragma unroll
      for (int k = 0; k < 4; ++k) {
        int row = k * 4 + prl;
        int crow = row < 14 ? row : 13;
        const float* hp = &Buf2[c * 256 + crow * 16 + cpc];
        float hv[9];
#pragma unroll
        for (int di = 0; di < 3; ++di)
#pragma unroll
          for (int dj = 0; dj < 3; ++dj) hv[di * 3 + dj] = hp[di * 16 + dj];
#pragma unroll
        for (int oo = 0; oo < 4; ++oo) {
          float s = acc[oo][k];
#pragma unroll
          for (int u = 0; u < 9; ++u) s += hv[u] * wr[oo][u];
          acc[oo][k] = s;
        }
      }
    }
    // d0 (Buf1) dead since the last sync; write d2 into Buf1
    if (pc2 < 14) {
#pragma unroll
      for (int k = 0; k < 4; ++k) {
        int row = k * 4 + prl;
        if (row < 14) {
#pragma unroll
          for (int oo = 0; oo < 4; ++oo)
            Buf1[(oq + oo) * 196 + row * 14 + pc2] =
                fmaxf(acc[oo][k] + b2[oq + oo], 0.f);
        }
      }
    }
  }
  __syncthreads();
  for (int e = t; e < 7200; e += TPB) Buf2[e] = 0.f;  // d3 padded [8][30][30]
  __syncthreads();

  // ---- deconv2: d2[16][14][14] -> d3[8][28][28]; wave = phase
  {
    const int tb = pa * 4 + pb;
    const float* wA = w3 + (size_t)tb * 128;
    const float* wB = w3 + (size_t)(tb + 2) * 128;
    const float* wC = w3 + (size_t)(tb + 8) * 128;
    const float* wD = w3 + (size_t)(tb + 10) * 128;
#pragma unroll 1
    for (int k = 0; k < 4; ++k) {
      const int px = lane + 64 * k;
      const int cpx = px < 196 ? px : 195;
      const int i = cpx / 14, j = cpx % 14;
      int ih[2], iw[2];
      float mh[2], mw[2];
#pragma unroll
      for (int s = 0; s < 2; ++s) {
        int v = i + pa + s - 1;
        mh[s] = (v >= 0 && v <= 13) ? 1.f : 0.f;
        ih[s] = v < 0 ? 0 : (v > 13 ? 13 : v);
        int u = j + pb + s - 1;
        mw[s] = (u >= 0 && u <= 13) ? 1.f : 0.f;
        iw[s] = u < 0 ? 0 : (u > 13 ? 13 : u);
      }
      const float m00 = mh[0] * mw[0], m01 = mh[0] * mw[1];
      const float m10 = mh[1] * mw[0], m11 = mh[1] * mw[1];
      float acc[8];
#pragma unroll
      for (int oo = 0; oo < 8; ++oo) acc[oo] = b3[oo];
#pragma unroll 2
      for (int c = 0; c < 16; ++c) {
        const float a00 = Buf1[c * 196 + ih[0] * 14 + iw[0]] * m00;
        const float a01 = Buf1[c * 196 + ih[0] * 14 + iw[1]] * m01;
        const float a10 = Buf1[c * 196 + ih[1] * 14 + iw[0]] * m10;
        const float a11 = Buf1[c * 196 + ih[1] * 14 + iw[1]] * m11;
        const int wb = c * 8;
#pragma unroll
        for (int oo = 0; oo < 8; ++oo)
          acc[oo] += a00 * wA[wb + oo] + a01 * wB[wb + oo] +
                     a10 * wC[wb + oo] + a11 * wD[wb + oo];
      }
      if (px < 196) {
        const int p = 2 * i + pa, q = 2 * j + pb;
        const int widx = (p + 1) * 30 + (q + 1);
#pragma unroll
        for (int oo = 0; oo < 8; ++oo)
          Buf2[oo * 900 + widx] = fmaxf(acc[oo], 0.f);
      }
    }
  }
  __syncthreads();

  // ---- final conv: d3[8][28][28] -> out[1][28][28], no relu
  for (int e = t; e < 784; e += TPB) {
    int p = e / 28, q = e - p * 28;
    float a = b4[0];
#pragma unroll
    for (int c = 0; c < 8; ++c) {
      const float* bp = &Buf2[c * 900 + p * 30 + q];
#pragma unroll
      for (int di = 0; di < 3; ++di)
#pragma unroll
        for (int dj = 0; dj < 3; ++dj)
          a += bp[di * 30 + dj] * w4[c * 9 + di * 3 + dj];
    }
    out[(size_t)b * 784 + e] = a;
  }
}

// ---------------------------------------------------------------------------
extern "C" void kernel_launch(void* const* d_in, const int* in_sizes, int n_in,
                              void* d_out, int out_size, void* d_ws,
                              size_t ws_size, hipStream_t stream) {
  const float* x      = (const float*)d_in[0];
  const float* ce_w1  = (const float*)d_in[1];
  const float* ce_b1  = (const float*)d_in[2];
  const float* ce_w2  = (const float*)d_in[3];
  const float* ce_b2  = (const float*)d_in[4];
  const float* ce_fcw = (const float*)d_in[5];
  const float* ce_fcb = (const float*)d_in[6];
  const float* ge_w1  = (const float*)d_in[7];
  const float* ge_b1  = (const float*)d_in[8];
  const float* ge_w2  = (const float*)d_in[9];
  const float* ge_b2  = (const float*)d_in[10];
  const float* ge_fcw = (const float*)d_in[11];
  const float* ge_fcb = (const float*)d_in[12];
  const float* memg   = (const float*)d_in[13];
  const float* dfcw   = (const float*)d_in[14];
  const float* dfcb   = (const float*)d_in[15];
  const float* d_w1   = (const float*)d_in[16];
  const float* d_b1   = (const float*)d_in[17];
  const float* d_w2   = (const float*)d_in[18];
  const float* d_b2   = (const float*)d_in[19];
  const float* d_w3   = (const float*)d_in[20];
  const float* d_b3   = (const float*)d_in[21];
  const float* d_w4   = (const float*)d_in[22];
  const float* d_b4   = (const float*)d_in[23];
  float* outp = (float*)d_out;

  // ws layout (floats): z[2048*128] | zmatch[2048*128] | invn[8192] | d0[2048*3136]
  float* ws     = (float*)d_ws;
  float* z      = ws;
  float* zmatch = ws + 262144;
  float* invn   = ws + 524288;
  float* d0ws   = ws + 532480;

  norm_kernel<<<2048, TPB, 0, stream>>>(memg, invn);
  encoder_kernel<14, 14, true><<<2048, TPB, 0, stream>>>(
      x, ce_w1, ce_b1, ce_w2, ce_b2, ce_fcw, ce_fcb, z, 0);
  encoder_kernel<28, 7, false><<<2048, TPB, 0, stream>>>(
      x, ge_w1, ge_b1, ge_w2, ge_b2, ge_fcw, ge_fcb, z, 64);
  match_kernel<<<256, TPB, 0, stream>>>(z, memg, invn, zmatch);
  decfc_kernel<<<dim3(25, 32), TPB, 0, stream>>>(zmatch, dfcw, dfcb, d0ws);
  decoder_kernel<<<2048, TPB, 0, stream>>>(d0ws, d_w1, d_b1, d_w2, d_b2, d_w3,
                                           d_b3, d_w4, d_b4, outp);
}

// Round 3
// 1103.918 us; speedup vs baseline: 2.6685x; 1.7482x over previous
//
#include <hip/hip_runtime.h>
#include <cfloat>
#include <cmath>

#define TPB 256

typedef _Float16 half8 __attribute__((ext_vector_type(8)));
typedef float floatx16 __attribute__((ext_vector_type(16)));

__device__ __forceinline__ float wave_reduce_sum(float v) {
#pragma unroll
  for (int off = 32; off > 0; off >>= 1) v += __shfl_xor(v, off, 64);
  return v;
}

// ---------------------------------------------------------------------------
// Kernel 0: build conv2 B-fragments (2-part f16 split) for both encoders.
// frag value B[k][n] = w2[n][c][tap], c = half*16 + k, k = kg*8+j.
// Storage: [enc][fragidx = ks*4+part*2+nt][lane][16B], lane = kg*32+n32.
// ---------------------------------------------------------------------------
__global__ __launch_bounds__(64) void prep_bfrags(
    const float* __restrict__ ce_w2, const float* __restrict__ ge_w2,
    float* __restrict__ frags) {
  const int blk = blockIdx.x;  // 144 = 2 enc x 72 frags
  const int enc = blk / 72;
  const int frag = blk % 72;
  const int ks = frag >> 2, part = (frag >> 1) & 1, nt = frag & 1;
  const int tap = ks >> 1, half = ks & 1;
  const int lane = threadIdx.x;
  const float* w2 = enc ? ge_w2 : ce_w2;
  const int n = nt * 32 + (lane & 31);
  const int cb = half * 16 + (lane >> 5) * 8;
  half8 out;
#pragma unroll
  for (int j = 0; j < 8; ++j) {
    float v = w2[(n * 32 + cb + j) * 9 + tap];
    _Float16 h = (_Float16)v;
    out[j] = (part == 0) ? h : (_Float16)((v - (float)h) * 4096.f);
  }
  *(half8*)((char*)frags + ((size_t)blk * 64 + lane) * 16) = out;
}

// ---------------------------------------------------------------------------
// Kernel 1: memory row inverse norms
// ---------------------------------------------------------------------------
__global__ __launch_bounds__(256) void norm_kernel(
    const float* __restrict__ memg, float* __restrict__ invn) {
  const int wv = threadIdx.x >> 6, lane = threadIdx.x & 63;
  const int row = blockIdx.x * 4 + wv;
  const float* r = memg + (size_t)row * 128;
  float a = r[lane], b = r[lane + 64];
  float s = wave_reduce_sum(a * a + b * b);
  if (lane == 0) invn[row] = 1.f / fmaxf(sqrtf(s), 1e-12f);
}

// ---------------------------------------------------------------------------
// Kernel 2: MFMA encoder. conv1 fp32 -> h1 split into 2 f16 parts (lo scaled
// by 2^12), channel-last LDS. conv2 = GEMM via v_mfma_f32_32x32x16_f16:
// D = Ah*Bh + 2^-12 (Ah*Bl' + Al'*Bh). Exact-enough: term err ~2^-22.
// Wave owns both N-tiles (n 0-31, 32-63); M-block = 2 tiles of 32 px.
// ---------------------------------------------------------------------------
template <int S, bool CENTER>
__global__ __launch_bounds__(256, 1) void encoder_mfma(
    const float* __restrict__ x, const float* __restrict__ w1,
    const float* __restrict__ b1, const float* __restrict__ b2,
    const float* __restrict__ fcw, const float* __restrict__ fcb,
    const float* __restrict__ bfrag, float* __restrict__ zout, int zoff) {
  constexpr int SP = S + 2;               // xs stride & h1 col count
  constexpr int NB = S / 14;              // bands of 14 output rows
  constexpr int PSTB = 16 * SP * 32 * 2;  // h1 part stride bytes
  constexpr int LIMIT = 14 * S;           // valid px per band
  constexpr int MTB = (LIMIT + 31) / 32;  // M-tiles per band (13 / 7)
  constexpr int NBLK = (MTB + 1) / 2;     // M-blocks per band

  __shared__ char Bs[73728];
  __shared__ char h1s[2 * PSTB];
  __shared__ float xs[SP * SP];
  __shared__ float w1s[288];
  __shared__ float featp[4][64];

  const int b = blockIdx.x;
  const int t = threadIdx.x;
  const int lane = t & 63;
  const int wv = t >> 6;

  // stage B fragments (coalesced b128) and input tile
  for (int e = t; e < 4608; e += TPB)
    ((float4*)Bs)[e] = ((const float4*)bfrag)[e];
  for (int e = t; e < SP * SP; e += TPB) xs[e] = 0.f;
  for (int e = t; e < 288; e += TPB) w1s[e] = w1[e];
  __syncthreads();
  const float* xb = x + (size_t)b * 784 + (CENTER ? (7 * 28 + 7) : 0);
  for (int e = t; e < S * S; e += TPB) {
    int i = e / S, j = e - i * S;
    xs[(i + 1) * SP + (j + 1)] = xb[i * 28 + j];
  }

  float sp0 = 0.f, sp1 = 0.f;
  const float bias0 = b2[lane & 31];
  const float bias1 = b2[32 + (lane & 31)];
  const char* bb0 = Bs + lane * 16;
  const char* bb1 = bb0 + 40960;

  for (int band = 0; band < NB; ++band) {
    const int b0 = band * 14;
    __syncthreads();  // h1 free (prev band done) + xs ready
    for (int e = t; e < (2 * PSTB) / 16; e += TPB)
      ((float4*)h1s)[e] = make_float4(0.f, 0.f, 0.f, 0.f);
    __syncthreads();
    // conv1: rows b0-1 .. b0+14, 8 channels per item, split to 2 f16 parts
    for (int e = t; e < 16 * S * 4; e += TPB) {
      int chq = e & 3;
      int rem = e >> 2;
      int gr = b0 - 1 + rem / S;
      int c = rem - (rem / S) * S;
      if (gr < 0 || gr >= S) continue;
      float xv[9];
#pragma unroll
      for (int di = 0; di < 3; ++di)
#pragma unroll
        for (int dj = 0; dj < 3; ++dj)
          xv[di * 3 + dj] = xs[(gr + di) * SP + (c + dj)];
      int lr = gr - b0 + 1;
      int ebase = ((lr * SP + (c + 1)) * 32 + chq * 8) * 2;  // bytes
      half8 hi8, lo8;
#pragma unroll
      for (int u = 0; u < 8; ++u) {
        int ch = chq * 8 + u;
        float a = b1[ch];
#pragma unroll
        for (int v = 0; v < 9; ++v) a += xv[v] * w1s[ch * 9 + v];
        a = fmaxf(a, 0.f);
        _Float16 h = (_Float16)a;
        hi8[u] = h;
        lo8[u] = (_Float16)((a - (float)h) * 4096.f);
      }
      *(half8*)(h1s + ebase) = hi8;
      *(half8*)(h1s + PSTB + ebase) = lo8;
    }
    __syncthreads();
    // conv2 MFMA: wave-strided M-blocks
    for (int mblk = wv; mblk < NBLK; mblk += 4) {
      const int Mt0 = mblk * 2;
      floatx16 acc[2][2][2] = {};  // [Mtile][Ntile][term hi/lo]
      int baseA[2];
#pragma unroll
      for (int im = 0; im < 2; ++im) {
        int px = (Mt0 + im) * 32 + (lane & 31);
        px = px < LIMIT ? px : LIMIT - 1;
        int lr = px / S;
        int c = px - lr * S;
        baseA[im] = (lr * SP + c) * 64 + (lane >> 5) * 16;
      }
#pragma unroll
      for (int tap = 0; tap < 9; ++tap) {
#pragma unroll
        for (int half = 0; half < 2; ++half) {
          const int ks = tap * 2 + half;
          const int offA = ((tap / 3) * SP + (tap % 3)) * 64 + half * 32;
          const char* bb = (ks < 10) ? bb0 : bb1;
          const int fo = (ks < 10) ? ks * 4096 : ks * 4096 - 40960;
          half8 bh0 = *(const half8*)(bb + fo);
          half8 bh1 = *(const half8*)(bb + fo + 1024);
          half8 bl0 = *(const half8*)(bb + fo + 2048);
          half8 bl1 = *(const half8*)(bb + fo + 3072);
#pragma unroll
          for (int im = 0; im < 2; ++im) {
            half8 ah = *(const half8*)(h1s + baseA[im] + offA);
            half8 al = *(const half8*)(h1s + PSTB + baseA[im] + offA);
            acc[im][0][0] = __builtin_amdgcn_mfma_f32_32x32x16_f16(
                ah, bh0, acc[im][0][0], 0, 0, 0);
            acc[im][1][0] = __builtin_amdgcn_mfma_f32_32x32x16_f16(
                ah, bh1, acc[im][1][0], 0, 0, 0);
            acc[im][0][1] = __builtin_amdgcn_mfma_f32_32x32x16_f16(
                ah, bl0, acc[im][0][1], 0, 0, 0);
            acc[im][0][1] = __builtin_amdgcn_mfma_f32_32x32x16_f16(
                al, bh0, acc[im][0][1], 0, 0, 0);
            acc[im][1][1] = __builtin_amdgcn_mfma_f32_32x32x16_f16(
                ah, bl1, acc[im][1][1], 0, 0, 0);
            acc[im][1][1] = __builtin_amdgcn_mfma_f32_32x32x16_f16(
                al, bh1, acc[im][1][1], 0, 0, 0);
          }
        }
      }
      // pool: feat[n] += relu(D + bias), D = acc_hi + acc_lo * 2^-12
#pragma unroll
      for (int im = 0; im < 2; ++im)
#pragma unroll
        for (int reg = 0; reg < 16; ++reg) {
          int row = (reg & 3) + 8 * (reg >> 2) + 4 * (lane >> 5);
          int p = (Mt0 + im) * 32 + row;
          if (p < LIMIT) {
            float v0 = acc[im][0][0][reg] + acc[im][0][1][reg] * (1.f / 4096.f) + bias0;
            float v1 = acc[im][1][0][reg] + acc[im][1][1][reg] * (1.f / 4096.f) + bias1;
            sp0 += fmaxf(v0, 0.f);
            sp1 += fmaxf(v1, 0.f);
          }
        }
    }
  }
  // reduce per-lane partials: lanes l and l^32 hold same n
  sp0 += __shfl_xor(sp0, 32);
  sp1 += __shfl_xor(sp1, 32);
  if (lane < 32) {
    featp[wv][lane] = sp0;
    featp[wv][32 + lane] = sp1;
  }
  __syncthreads();
  if (t < 64)
    featp[0][t] = (featp[0][t] + featp[1][t] + featp[2][t] + featp[3][t]) *
                  (1.f / (S * S));
  __syncthreads();
  if (t < 64) {
    float s = 0.f;
#pragma unroll
    for (int i = 0; i < 64; ++i) s += featp[0][i] * fcw[t * 64 + i];
    zout[(size_t)b * 128 + zoff + t] = s + fcb[t];
  }
}

// ---------------------------------------------------------------------------
// Kernel 3: fused cosine-sim / top-10 / softmax / memory blend (unchanged)
// ---------------------------------------------------------------------------
__global__ __launch_bounds__(256) void match_kernel(
    const float* __restrict__ z, const float* __restrict__ memg,
    const float* __restrict__ invn, float* __restrict__ zmatch) {
  __shared__ __align__(16) float zs[8][128];
  __shared__ float qv[8][512];
  __shared__ int qi[8][512];
  __shared__ int qn[8];
  __shared__ float rowmin[8];
  __shared__ float topw[8][10];
  __shared__ int topidx[8][10];

  const int t = threadIdx.x;
  const int rowbase = blockIdx.x * 8;

  for (int e = t; e < 8 * 128; e += TPB) {
    int r = e >> 7, j = e & 127;
    zs[r][j] = z[(size_t)(rowbase + r) * 128 + j];
  }
  if (t < 8) { qn[t] = 0; rowmin[t] = -FLT_MAX; }
  __syncthreads();
  {
    int wv = t >> 6, lane = t & 63;
#pragma unroll
    for (int h = 0; h < 2; ++h) {
      int r = wv + h * 4;
      float a = zs[r][lane], b = zs[r][lane + 64];
      float s = wave_reduce_sum(a * a + b * b);
      float inv = 1.f / fmaxf(sqrtf(s), 1e-12f);
      zs[r][lane] = a * inv;
      zs[r][lane + 64] = b * inv;
    }
  }
  __syncthreads();

  float av[10];
  int ai[10];
#pragma unroll
  for (int i = 0; i < 10; ++i) { av[i] = -FLT_MAX; ai[i] = 0; }

  for (int mt = 0; mt < 16; ++mt) {
    int m0 = mt * 512 + t;
    float acc0[8] = {}, acc1[8] = {};
    const float4* mr0 = (const float4*)(memg + (size_t)m0 * 128);
    const float4* mr1 = (const float4*)(memg + (size_t)(m0 + 256) * 128);
#pragma unroll 4
    for (int jq = 0; jq < 32; ++jq) {
      float4 a0 = mr0[jq], a1 = mr1[jq];
#pragma unroll
      for (int r = 0; r < 8; ++r) {
        float4 zv = ((const float4*)zs[r])[jq];
        acc0[r] += a0.x * zv.x + a0.y * zv.y + a0.z * zv.z + a0.w * zv.w;
        acc1[r] += a1.x * zv.x + a1.y * zv.y + a1.z * zv.z + a1.w * zv.w;
      }
    }
    float i0 = invn[m0], i1 = invn[m0 + 256];
#pragma unroll
    for (int r = 0; r < 8; ++r) {
      float rm = rowmin[r];
      float v0 = acc0[r] * i0;
      if (v0 > rm) {
        int k = atomicAdd(&qn[r], 1);
        qv[r][k] = v0; qi[r][k] = m0;
      }
      float v1 = acc1[r] * i1;
      if (v1 > rm) {
        int k = atomicAdd(&qn[r], 1);
        qv[r][k] = v1; qi[r][k] = m0 + 256;
      }
    }
    __syncthreads();
    if (t < 8) {
      int n = qn[t];
      for (int k = 0; k < n; ++k) {
        float v = qv[t][k];
        int m = qi[t][k];
        if (v > av[9]) {
#pragma unroll
          for (int i = 0; i < 10; ++i) {
            if (v > av[i]) {
              float tv = av[i]; av[i] = v; v = tv;
              int ti = ai[i]; ai[i] = m; m = ti;
            }
          }
        }
      }
      qn[t] = 0;
      rowmin[t] = av[9];
    }
    __syncthreads();
  }

  if (t < 8) {
    float e_[10], s = 0.f;
#pragma unroll
    for (int k = 0; k < 10; ++k) { e_[k] = expf(av[k]); s += e_[k]; }
    float inv = 1.f / s;
#pragma unroll
    for (int k = 0; k < 10; ++k) { topw[t][k] = e_[k] * inv; topidx[t][k] = ai[k]; }
  }
  __syncthreads();
  for (int e = t; e < 8 * 128; e += TPB) {
    int r = e >> 7, d = e & 127;
    float o = 0.f;
#pragma unroll
    for (int k = 0; k < 10; ++k)
      o += topw[r][k] * memg[(size_t)topidx[r][k] * 128 + d];
    zmatch[(size_t)(rowbase + r) * 128 + d] = o;
  }
}

// ---------------------------------------------------------------------------
// Kernel 4: decoder FC GEMM (unchanged)
// ---------------------------------------------------------------------------
__global__ __launch_bounds__(256) void decfc_kernel(
    const float* __restrict__ zmatch, const float* __restrict__ fcw,
    const float* __restrict__ fcb, float* __restrict__ d0ws) {
  __shared__ __align__(16) float zt[64][128];
  const int t = threadIdx.x;
  const int c0 = blockIdx.x * 128;
  const int r0 = blockIdx.y * 64;
  {
    float4* zt4 = (float4*)&zt[0][0];
    const float4* zm4 = (const float4*)(zmatch + (size_t)r0 * 128);
    for (int e = t; e < 2048; e += TPB) zt4[e] = zm4[e];
  }
  __syncthreads();
  const int cg = (t & 31) * 4;
  const int rg = t >> 5;
  float acc[8][4] = {};
  for (int j = 0; j < 128; j += 4) {
    float4 wv[4];
#pragma unroll
    for (int c = 0; c < 4; ++c) {
      int col = c0 + cg + c;
      wv[c] = (col < 3136) ? *(const float4*)(fcw + (size_t)col * 128 + j)
                           : make_float4(0.f, 0.f, 0.f, 0.f);
    }
#pragma unroll
    for (int k = 0; k < 8; ++k) {
      float4 zv = *(const float4*)&zt[rg * 8 + k][j];
#pragma unroll
      for (int c = 0; c < 4; ++c)
        acc[k][c] += wv[c].x * zv.x + wv[c].y * zv.y + wv[c].z * zv.z + wv[c].w * zv.w;
    }
  }
#pragma unroll
  for (int k = 0; k < 8; ++k) {
    int row = r0 + rg * 8 + k;
#pragma unroll
    for (int c = 0; c < 4; ++c) {
      int col = c0 + cg + c;
      if (col < 3136) d0ws[(size_t)row * 3136 + col] = acc[k][c] + fcb[col];
    }
  }
}

// ---------------------------------------------------------------------------
// Kernel 5: fused decoder v2 (unchanged from r2)
// ---------------------------------------------------------------------------
__global__ __launch_bounds__(256) void decoder_kernel(
    const float* __restrict__ d0g, const float* __restrict__ w1,
    const float* __restrict__ b1, const float* __restrict__ w2,
    const float* __restrict__ b2, const float* __restrict__ w3,
    const float* __restrict__ b3, const float* __restrict__ w4,
    const float* __restrict__ b4, float* __restrict__ out) {
  __shared__ float Buf1[3136];
  __shared__ float Buf2[8192];

  const int b = blockIdx.x;
  const int t = threadIdx.x;
  const int lane = t & 63;
  const int ph = __builtin_amdgcn_readfirstlane(t >> 6);
  const int pa = ph >> 1, pb = ph & 1;

  for (int e = t; e < 3136; e += TPB) Buf1[e] = d0g[(size_t)b * 3136 + e];
  for (int e = t; e < 8192; e += TPB) Buf2[e] = 0.f;
  __syncthreads();

  {
    const int i = lane / 7, j = lane % 7;
    const int p = 2 * i + pa, q = 2 * j + pb;
    int ih[2], iw[2];
    float mh[2], mw[2];
#pragma unroll
    for (int s = 0; s < 2; ++s) {
      int v = i + pa + s - 1;
      mh[s] = (v >= 0 && v <= 6) ? 1.f : 0.f;
      ih[s] = v < 0 ? 0 : (v > 6 ? 6 : v);
      int u = j + pb + s - 1;
      mw[s] = (u >= 0 && u <= 6) ? 1.f : 0.f;
      iw[s] = u < 0 ? 0 : (u > 6 ? 6 : u);
    }
    const float m00 = mh[0] * mw[0], m01 = mh[0] * mw[1];
    const float m10 = mh[1] * mw[0], m11 = mh[1] * mw[1];
    const int tb = pa * 4 + pb;
    const float* wA = w1 + (size_t)tb * 2048;
    const float* wB = w1 + (size_t)(tb + 2) * 2048;
    const float* wC = w1 + (size_t)(tb + 8) * 2048;
    const float* wD = w1 + (size_t)(tb + 10) * 2048;
#pragma unroll 1
    for (int half = 0; half < 2; ++half) {
      const int o0 = half * 16;
      float acc[16];
#pragma unroll
      for (int oo = 0; oo < 16; ++oo) acc[oo] = b1[o0 + oo];
#pragma unroll 2
      for (int c = 0; c < 64; ++c) {
        const float a00 = Buf1[c * 49 + ih[0] * 7 + iw[0]] * m00;
        const float a01 = Buf1[c * 49 + ih[0] * 7 + iw[1]] * m01;
        const float a10 = Buf1[c * 49 + ih[1] * 7 + iw[0]] * m10;
        const float a11 = Buf1[c * 49 + ih[1] * 7 + iw[1]] * m11;
        const int wb = c * 32 + o0;
#pragma unroll
        for (int oo = 0; oo < 16; ++oo)
          acc[oo] += a00 * wA[wb + oo] + a01 * wB[wb + oo] +
                     a10 * wC[wb + oo] + a11 * wD[wb + oo];
      }
      if (lane < 49) {
        const int widx = (p + 1) * 16 + (q + 1);
#pragma unroll
        for (int oo = 0; oo < 16; ++oo)
          Buf2[(o0 + oo) * 256 + widx] = fmaxf(acc[oo], 0.f);
      }
    }
  }
  __syncthreads();

  {
    const int oq = __builtin_amdgcn_readfirstlane((t >> 6) * 4);
    const int pc2 = lane & 15, prl = lane >> 4;
    const int cpc = pc2 < 14 ? pc2 : 13;
    float acc[4][4] = {};
#pragma unroll 1
    for (int c = 0; c < 32; ++c) {
      float wr[4][9];
#pragma unroll
      for (int oo = 0; oo < 4; ++oo)
#pragma unroll
        for (int u = 0; u < 9; ++u)
          wr[oo][u] = w2[((oq + oo) * 32 + c) * 9 + u];
#pragma unroll
      for (int k = 0; k < 4; ++k) {
        int row = k * 4 + prl;
        int crow = row < 14 ? row : 13;
        const float* hp = &Buf2[c * 256 + crow * 16 + cpc];
        float hv[9];
#pragma unroll
        for (int di = 0; di < 3; ++di)
#pragma unroll
          for (int dj = 0; dj < 3; ++dj) hv[di * 3 + dj] = hp[di * 16 + dj];
#pragma unroll
        for (int oo = 0; oo < 4; ++oo) {
          float s = acc[oo][k];
#pragma unroll
          for (int u = 0; u < 9; ++u) s += hv[u] * wr[oo][u];
          acc[oo][k] = s;
        }
      }
    }
    if (pc2 < 14) {
#pragma unroll
      for (int k = 0; k < 4; ++k) {
        int row = k * 4 + prl;
        if (row < 14) {
#pragma unroll
          for (int oo = 0; oo < 4; ++oo)
            Buf1[(oq + oo) * 196 + row * 14 + pc2] =
                fmaxf(acc[oo][k] + b2[oq + oo], 0.f);
        }
      }
    }
  }
  __syncthreads();
  for (int e = t; e < 7200; e += TPB) Buf2[e] = 0.f;
  __syncthreads();

  {
    const int tb = pa * 4 + pb;
    const float* wA = w3 + (size_t)tb * 128;
    const float* wB = w3 + (size_t)(tb + 2) * 128;
    const float* wC = w3 + (size_t)(tb + 8) * 128;
    const float* wD = w3 + (size_t)(tb + 10) * 128;
#pragma unroll 1
    for (int k = 0; k < 4; ++k) {
      const int px = lane + 64 * k;
      const int cpx = px < 196 ? px : 195;
      const int i = cpx / 14, j = cpx % 14;
      int ih[2], iw[2];
      float mh[2], mw[2];
#pragma unroll
      for (int s = 0; s < 2; ++s) {
        int v = i + pa + s - 1;
        mh[s] = (v >= 0 && v <= 13) ? 1.f : 0.f;
        ih[s] = v < 0 ? 0 : (v > 13 ? 13 : v);
        int u = j + pb + s - 1;
        mw[s] = (u >= 0 && u <= 13) ? 1.f : 0.f;
        iw[s] = u < 0 ? 0 : (u > 13 ? 13 : u);
      }
      const float m00 = mh[0] * mw[0], m01 = mh[0] * mw[1];
      const float m10 = mh[1] * mw[0], m11 = mh[1] * mw[1];
      float acc[8];
#pragma unroll
      for (int oo = 0; oo < 8; ++oo) acc[oo] = b3[oo];
#pragma unroll 2
      for (int c = 0; c < 16; ++c) {
        const float a00 = Buf1[c * 196 + ih[0] * 14 + iw[0]] * m00;
        const float a01 = Buf1[c * 196 + ih[0] * 14 + iw[1]] * m01;
        const float a10 = Buf1[c * 196 + ih[1] * 14 + iw[0]] * m10;
        const float a11 = Buf1[c * 196 + ih[1] * 14 + iw[1]] * m11;
        const int wb = c * 8;
#pragma unroll
        for (int oo = 0; oo < 8; ++oo)
          acc[oo] += a00 * wA[wb + oo] + a01 * wB[wb + oo] +
                     a10 * wC[wb + oo] + a11 * wD[wb + oo];
      }
      if (px < 196) {
        const int p = 2 * i + pa, q = 2 * j + pb;
        const int widx = (p + 1) * 30 + (q + 1);
#pragma unroll
        for (int oo = 0; oo < 8; ++oo)
          Buf2[oo * 900 + widx] = fmaxf(acc[oo], 0.f);
      }
    }
  }
  __syncthreads();

  for (int e = t; e < 784; e += TPB) {
    int p = e / 28, q = e - p * 28;
    float a = b4[0];
#pragma unroll
    for (int c = 0; c < 8; ++c) {
      const float* bp = &Buf2[c * 900 + p * 30 + q];
#pragma unroll
      for (int di = 0; di < 3; ++di)
#pragma unroll
        for (int dj = 0; dj < 3; ++dj)
          a += bp[di * 30 + dj] * w4[c * 9 + di * 3 + dj];
    }
    out[(size_t)b * 784 + e] = a;
  }
}

// ---------------------------------------------------------------------------
extern "C" void kernel_launch(void* const* d_in, const int* in_sizes, int n_in,
                              void* d_out, int out_size, void* d_ws,
                              size_t ws_size, hipStream_t stream) {
  const float* x      = (const float*)d_in[0];
  const float* ce_w1  = (const float*)d_in[1];
  const float* ce_b1  = (const float*)d_in[2];
  const float* ce_w2  = (const float*)d_in[3];
  const float* ce_b2  = (const float*)d_in[4];
  const float* ce_fcw = (const float*)d_in[5];
  const float* ce_fcb = (const float*)d_in[6];
  const float* ge_w1  = (const float*)d_in[7];
  const float* ge_b1  = (const float*)d_in[8];
  const float* ge_w2  = (const float*)d_in[9];
  const float* ge_b2  = (const float*)d_in[10];
  const float* ge_fcw = (const float*)d_in[11];
  const float* ge_fcb = (const float*)d_in[12];
  const float* memg   = (const float*)d_in[13];
  const float* dfcw   = (const float*)d_in[14];
  const float* dfcb   = (const float*)d_in[15];
  const float* d_w1   = (const float*)d_in[16];
  const float* d_b1   = (const float*)d_in[17];
  const float* d_w2   = (const float*)d_in[18];
  const float* d_b2   = (const float*)d_in[19];
  const float* d_w3   = (const float*)d_in[20];
  const float* d_b3   = (const float*)d_in[21];
  const float* d_w4   = (const float*)d_in[22];
  const float* d_b4   = (const float*)d_in[23];
  float* outp = (float*)d_out;

  // ws layout (floats): z[262144] | zmatch[262144] | invn[8192] |
  // frags[36864] (lifetime: prep->encoders) overlapping-free region, then
  // d0ws[2048*3136] reuses frag region start (disjoint lifetimes).
  float* ws     = (float*)d_ws;
  float* z      = ws;
  float* zmatch = ws + 262144;
  float* invn   = ws + 524288;
  float* frags  = ws + 532480;            // 36864 floats (2 enc x 73728 B)
  float* d0ws   = ws + 532480 + 36864;    // after frags

  prep_bfrags<<<144, 64, 0, stream>>>(ce_w2, ge_w2, frags);
  norm_kernel<<<2048, TPB, 0, stream>>>(memg, invn);
  encoder_mfma<14, true><<<2048, TPB, 0, stream>>>(
      x, ce_w1, ce_b1, ce_b2, ce_fcw, ce_fcb, frags, z, 0);
  encoder_mfma<28, false><<<2048, TPB, 0, stream>>>(
      x, ge_w1, ge_b1, ge_b2, ge_fcw, ge_fcb, frags + 18432, z, 64);
  match_kernel<<<256, TPB, 0, stream>>>(z, memg, invn, zmatch);
  decfc_kernel<<<dim3(25, 32), TPB, 0, stream>>>(zmatch, dfcw, dfcb, d0ws);
  decoder_kernel<<<2048, TPB, 0, stream>>>(d0ws, d_w1, d_b1, d_w2, d_b2, d_w3,
                                           d_b3, d_w4, d_b4, outp);
}

// Round 4
// 1056.008 us; speedup vs baseline: 2.7896x; 1.0454x over previous
//
#include <hip/hip_runtime.h>
#include <cfloat>
#include <cmath>

#define TPB 256

typedef _Float16 half8 __attribute__((ext_vector_type(8)));
typedef float floatx16 __attribute__((ext_vector_type(16)));

__device__ __forceinline__ float wave_reduce_sum(float v) {
#pragma unroll
  for (int off = 32; off > 0; off >>= 1) v += __shfl_xor(v, off, 64);
  return v;
}

// ---------------------------------------------------------------------------
// Kernel 0: build conv2 B-fragments (2-part f16 split) for both encoders.
// ---------------------------------------------------------------------------
__global__ __launch_bounds__(64) void prep_bfrags(
    const float* __restrict__ ce_w2, const float* __restrict__ ge_w2,
    float* __restrict__ frags) {
  const int blk = blockIdx.x;  // 144 = 2 enc x 72 frags
  const int enc = blk / 72;
  const int frag = blk % 72;
  const int ks = frag >> 2, part = (frag >> 1) & 1, nt = frag & 1;
  const int tap = ks >> 1, half = ks & 1;
  const int lane = threadIdx.x;
  const float* w2 = enc ? ge_w2 : ce_w2;
  const int n = nt * 32 + (lane & 31);
  const int cb = half * 16 + (lane >> 5) * 8;
  half8 out;
#pragma unroll
  for (int j = 0; j < 8; ++j) {
    float v = w2[(n * 32 + cb + j) * 9 + tap];
    _Float16 h = (_Float16)v;
    out[j] = (part == 0) ? h : (_Float16)((v - (float)h) * 4096.f);
  }
  *(half8*)((char*)frags + ((size_t)blk * 64 + lane) * 16) = out;
}

// ---------------------------------------------------------------------------
// Kernel 1: memory row inverse norms
// ---------------------------------------------------------------------------
__global__ __launch_bounds__(256) void norm_kernel(
    const float* __restrict__ memg, float* __restrict__ invn) {
  const int wv = threadIdx.x >> 6, lane = threadIdx.x & 63;
  const int row = blockIdx.x * 4 + wv;
  const float* r = memg + (size_t)row * 128;
  float a = r[lane], b = r[lane + 64];
  float s = wave_reduce_sum(a * a + b * b);
  if (lane == 0) invn[row] = 1.f / fmaxf(sqrtf(s), 1e-12f);
}

// ---------------------------------------------------------------------------
// Kernel 2: MFMA encoder body (shared by both encoders, fused launch).
// conv1 fp32 -> h1 split into 2 f16 parts (lo scaled 2^12), channel-last LDS.
// conv2 GEMM via v_mfma_f32_32x32x16_f16: D = Ah*Bh + 2^-12(Ah*Bl' + Al'*Bh).
// ---------------------------------------------------------------------------
template <int S, bool CENTER>
__device__ __forceinline__ void encoder_body(
    char* smem, const float* __restrict__ x, const float* __restrict__ w1,
    const float* __restrict__ b1, const float* __restrict__ b2,
    const float* __restrict__ fcw, const float* __restrict__ fcb,
    const float* __restrict__ bfrag, float* __restrict__ zout, int zoff,
    int b) {
  constexpr int SP = S + 2;
  constexpr int NB = S / 14;
  constexpr int PSTB = 16 * SP * 32 * 2;
  constexpr int LIMIT = 14 * S;
  constexpr int MTB = (LIMIT + 31) / 32;
  constexpr int NBLK = (MTB + 1) / 2;

  char* Bs = smem;
  char* h1s = smem + 73728;
  float* xs = (float*)(h1s + 2 * PSTB);
  float* w1s = xs + SP * SP;
  float(*featp)[64] = (float(*)[64])(w1s + 288);

  const int t = threadIdx.x;
  const int lane = t & 63;
  const int wv = t >> 6;

  for (int e = t; e < 4608; e += TPB)
    ((float4*)Bs)[e] = ((const float4*)bfrag)[e];
  for (int e = t; e < SP * SP; e += TPB) xs[e] = 0.f;
  for (int e = t; e < 288; e += TPB) w1s[e] = w1[e];
  __syncthreads();
  const float* xb = x + (size_t)b * 784 + (CENTER ? (7 * 28 + 7) : 0);
  for (int e = t; e < S * S; e += TPB) {
    int i = e / S, j = e - i * S;
    xs[(i + 1) * SP + (j + 1)] = xb[i * 28 + j];
  }

  float sp0 = 0.f, sp1 = 0.f;
  const float bias0 = b2[lane & 31];
  const float bias1 = b2[32 + (lane & 31)];
  const char* bb0 = Bs + lane * 16;
  const char* bb1 = bb0 + 40960;

  for (int band = 0; band < NB; ++band) {
    const int b0 = band * 14;
    __syncthreads();
    for (int e = t; e < (2 * PSTB) / 16; e += TPB)
      ((float4*)h1s)[e] = make_float4(0.f, 0.f, 0.f, 0.f);
    __syncthreads();
    for (int e = t; e < 16 * S * 4; e += TPB) {
      int chq = e & 3;
      int rem = e >> 2;
      int gr = b0 - 1 + rem / S;
      int c = rem - (rem / S) * S;
      if (gr < 0 || gr >= S) continue;
      float xv[9];
#pragma unroll
      for (int di = 0; di < 3; ++di)
#pragma unroll
        for (int dj = 0; dj < 3; ++dj)
          xv[di * 3 + dj] = xs[(gr + di) * SP + (c + dj)];
      int lr = gr - b0 + 1;
      int ebase = ((lr * SP + (c + 1)) * 32 + chq * 8) * 2;
      half8 hi8, lo8;
#pragma unroll
      for (int u = 0; u < 8; ++u) {
        int ch = chq * 8 + u;
        float a = b1[ch];
#pragma unroll
        for (int v = 0; v < 9; ++v) a += xv[v] * w1s[ch * 9 + v];
        a = fmaxf(a, 0.f);
        _Float16 h = (_Float16)a;
        hi8[u] = h;
        lo8[u] = (_Float16)((a - (float)h) * 4096.f);
      }
      *(half8*)(h1s + ebase) = hi8;
      *(half8*)(h1s + PSTB + ebase) = lo8;
    }
    __syncthreads();
    for (int mblk = wv; mblk < NBLK; mblk += 4) {
      const int Mt0 = mblk * 2;
      floatx16 acc[2][2][2] = {};
      int baseA[2];
#pragma unroll
      for (int im = 0; im < 2; ++im) {
        int px = (Mt0 + im) * 32 + (lane & 31);
        px = px < LIMIT ? px : LIMIT - 1;
        int lr = px / S;
        int c = px - lr * S;
        baseA[im] = (lr * SP + c) * 64 + (lane >> 5) * 16;
      }
#pragma unroll
      for (int tap = 0; tap < 9; ++tap) {
#pragma unroll
        for (int half = 0; half < 2; ++half) {
          const int ks = tap * 2 + half;
          const int offA = ((tap / 3) * SP + (tap % 3)) * 64 + half * 32;
          const char* bb = (ks < 10) ? bb0 : bb1;
          const int fo = (ks < 10) ? ks * 4096 : ks * 4096 - 40960;
          half8 bh0 = *(const half8*)(bb + fo);
          half8 bh1 = *(const half8*)(bb + fo + 1024);
          half8 bl0 = *(const half8*)(bb + fo + 2048);
          half8 bl1 = *(const half8*)(bb + fo + 3072);
#pragma unroll
          for (int im = 0; im < 2; ++im) {
            half8 ah = *(const half8*)(h1s + baseA[im] + offA);
            half8 al = *(const half8*)(h1s + PSTB + baseA[im] + offA);
            acc[im][0][0] = __builtin_amdgcn_mfma_f32_32x32x16_f16(
                ah, bh0, acc[im][0][0], 0, 0, 0);
            acc[im][1][0] = __builtin_amdgcn_mfma_f32_32x32x16_f16(
                ah, bh1, acc[im][1][0], 0, 0, 0);
            acc[im][0][1] = __builtin_amdgcn_mfma_f32_32x32x16_f16(
                ah, bl0, acc[im][0][1], 0, 0, 0);
            acc[im][0][1] = __builtin_amdgcn_mfma_f32_32x32x16_f16(
                al, bh0, acc[im][0][1], 0, 0, 0);
            acc[im][1][1] = __builtin_amdgcn_mfma_f32_32x32x16_f16(
                ah, bl1, acc[im][1][1], 0, 0, 0);
            acc[im][1][1] = __builtin_amdgcn_mfma_f32_32x32x16_f16(
                al, bh1, acc[im][1][1], 0, 0, 0);
          }
        }
      }
#pragma unroll
      for (int im = 0; im < 2; ++im)
#pragma unroll
        for (int reg = 0; reg < 16; ++reg) {
          int row = (reg & 3) + 8 * (reg >> 2) + 4 * (lane >> 5);
          int p = (Mt0 + im) * 32 + row;
          if (p < LIMIT) {
            float v0 =
                acc[im][0][0][reg] + acc[im][0][1][reg] * (1.f / 4096.f) + bias0;
            float v1 =
                acc[im][1][0][reg] + acc[im][1][1][reg] * (1.f / 4096.f) + bias1;
            sp0 += fmaxf(v0, 0.f);
            sp1 += fmaxf(v1, 0.f);
          }
        }
    }
  }
  sp0 += __shfl_xor(sp0, 32);
  sp1 += __shfl_xor(sp1, 32);
  if (lane < 32) {
    featp[wv][lane] = sp0;
    featp[wv][32 + lane] = sp1;
  }
  __syncthreads();
  if (t < 64)
    featp[0][t] = (featp[0][t] + featp[1][t] + featp[2][t] + featp[3][t]) *
                  (1.f / (S * S));
  __syncthreads();
  if (t < 64) {
    float s = 0.f;
#pragma unroll
    for (int i = 0; i < 64; ++i) s += featp[0][i] * fcw[t * 64 + i];
    zout[(size_t)b * 128 + zoff + t] = s + fcb[t];
  }
}

// Fused launch: blocks 0..2047 = global encoder, 2048..4095 = center encoder.
__global__ __launch_bounds__(256, 1) void encoders_fused(
    const float* __restrict__ x, const float* __restrict__ ce_w1,
    const float* __restrict__ ce_b1, const float* __restrict__ ce_b2,
    const float* __restrict__ ce_fcw, const float* __restrict__ ce_fcb,
    const float* __restrict__ ge_w1, const float* __restrict__ ge_b1,
    const float* __restrict__ ge_b2, const float* __restrict__ ge_fcw,
    const float* __restrict__ ge_fcb, const float* __restrict__ frags,
    float* __restrict__ z) {
  __shared__ __align__(16) char smem[140944];
  if (blockIdx.x < 2048)
    encoder_body<28, false>(smem, x, ge_w1, ge_b1, ge_b2, ge_fcw, ge_fcb,
                            frags + 18432, z, 64, blockIdx.x);
  else
    encoder_body<14, true>(smem, x, ce_w1, ce_b1, ce_b2, ce_fcw, ce_fcb, frags,
                           z, 0, blockIdx.x - 2048);
}

// ---------------------------------------------------------------------------
// Kernel 3a: partial match. Grid (256 z-groups, 4 mem-quarters). Each block:
// 8 z-rows vs 2048 mem rows -> exact per-quarter top-10 per row to ws.
// ---------------------------------------------------------------------------
__global__ __launch_bounds__(256) void match_part(
    const float* __restrict__ z, const float* __restrict__ memg,
    const float* __restrict__ invn, float* __restrict__ topvw,
    int* __restrict__ topiw) {
  __shared__ __align__(16) float zs[8][128];
  __shared__ float qv[8][512];
  __shared__ int qi[8][512];
  __shared__ int qn[8];
  __shared__ float rowmin[8];

  const int t = threadIdx.x;
  const int rowbase = blockIdx.x * 8;
  const int mbase = blockIdx.y * 2048;

  for (int e = t; e < 8 * 128; e += TPB) {
    int r = e >> 7, j = e & 127;
    zs[r][j] = z[(size_t)(rowbase + r) * 128 + j];
  }
  if (t < 8) { qn[t] = 0; rowmin[t] = -FLT_MAX; }
  __syncthreads();
  {
    int wv = t >> 6, lane = t & 63;
#pragma unroll
    for (int h = 0; h < 2; ++h) {
      int r = wv + h * 4;
      float a = zs[r][lane], b = zs[r][lane + 64];
      float s = wave_reduce_sum(a * a + b * b);
      float inv = 1.f / fmaxf(sqrtf(s), 1e-12f);
      zs[r][lane] = a * inv;
      zs[r][lane + 64] = b * inv;
    }
  }
  __syncthreads();

  float av[10];
  int ai[10];
#pragma unroll
  for (int i = 0; i < 10; ++i) { av[i] = -FLT_MAX; ai[i] = 0; }

  for (int mt = 0; mt < 4; ++mt) {
    int m0 = mbase + mt * 512 + t;
    float acc0[8] = {}, acc1[8] = {};
    const float4* mr0 = (const float4*)(memg + (size_t)m0 * 128);
    const float4* mr1 = (const float4*)(memg + (size_t)(m0 + 256) * 128);
#pragma unroll 4
    for (int jq = 0; jq < 32; ++jq) {
      float4 a0 = mr0[jq], a1 = mr1[jq];
#pragma unroll
      for (int r = 0; r < 8; ++r) {
        float4 zv = ((const float4*)zs[r])[jq];
        acc0[r] += a0.x * zv.x + a0.y * zv.y + a0.z * zv.z + a0.w * zv.w;
        acc1[r] += a1.x * zv.x + a1.y * zv.y + a1.z * zv.z + a1.w * zv.w;
      }
    }
    float i0 = invn[m0], i1 = invn[m0 + 256];
#pragma unroll
    for (int r = 0; r < 8; ++r) {
      float rm = rowmin[r];
      float v0 = acc0[r] * i0;
      if (v0 > rm) {
        int k = atomicAdd(&qn[r], 1);
        qv[r][k] = v0; qi[r][k] = m0;
      }
      float v1 = acc1[r] * i1;
      if (v1 > rm) {
        int k = atomicAdd(&qn[r], 1);
        qv[r][k] = v1; qi[r][k] = m0 + 256;
      }
    }
    __syncthreads();
    if (t < 8) {
      int n = qn[t];
      for (int k = 0; k < n; ++k) {
        float v = qv[t][k];
        int m = qi[t][k];
        if (v > av[9]) {
#pragma unroll
          for (int i = 0; i < 10; ++i) {
            if (v > av[i]) {
              float tv = av[i]; av[i] = v; v = tv;
              int ti = ai[i]; ai[i] = m; m = ti;
            }
          }
        }
      }
      qn[t] = 0;
      rowmin[t] = av[9];
    }
    __syncthreads();
  }

  if (t < 8) {
    const size_t base = (size_t)(rowbase + t) * 40 + blockIdx.y * 10;
#pragma unroll
    for (int k = 0; k < 10; ++k) {
      topvw[base + k] = av[k];
      topiw[base + k] = ai[k];
    }
  }
}

// ---------------------------------------------------------------------------
// Kernel 3b: merge 4x10 candidates -> exact top-10 -> softmax -> blend.
// ---------------------------------------------------------------------------
__global__ __launch_bounds__(256) void match_merge(
    const float* __restrict__ topvw, const int* __restrict__ topiw,
    const float* __restrict__ memg, float* __restrict__ zmatch) {
  __shared__ float topw[8][10];
  __shared__ int topidx[8][10];
  const int t = threadIdx.x;
  const int rowbase = blockIdx.x * 8;

  if (t < 8) {
    float av[10];
    int ai[10];
#pragma unroll
    for (int i = 0; i < 10; ++i) { av[i] = -FLT_MAX; ai[i] = 0; }
    const size_t base = (size_t)(rowbase + t) * 40;
    for (int c = 0; c < 40; ++c) {
      float v = topvw[base + c];
      int m = topiw[base + c];
      if (v > av[9]) {
#pragma unroll
        for (int i = 0; i < 10; ++i) {
          if (v > av[i]) {
            float tv = av[i]; av[i] = v; v = tv;
            int ti = ai[i]; ai[i] = m; m = ti;
          }
        }
      }
    }
    float e_[10], s = 0.f;
#pragma unroll
    for (int k = 0; k < 10; ++k) { e_[k] = expf(av[k]); s += e_[k]; }
    float inv = 1.f / s;
#pragma unroll
    for (int k = 0; k < 10; ++k) { topw[t][k] = e_[k] * inv; topidx[t][k] = ai[k]; }
  }
  __syncthreads();
  for (int e = t; e < 8 * 128; e += TPB) {
    int r = e >> 7, d = e & 127;
    float o = 0.f;
#pragma unroll
    for (int k = 0; k < 10; ++k)
      o += topw[r][k] * memg[(size_t)topidx[r][k] * 128 + d];
    zmatch[(size_t)(rowbase + r) * 128 + d] = o;
  }
}

// ---------------------------------------------------------------------------
// Kernel 4: decoder FC GEMM (unchanged)
// ---------------------------------------------------------------------------
__global__ __launch_bounds__(256) void decfc_kernel(
    const float* __restrict__ zmatch, const float* __restrict__ fcw,
    const float* __restrict__ fcb, float* __restrict__ d0ws) {
  __shared__ __align__(16) float zt[64][128];
  const int t = threadIdx.x;
  const int c0 = blockIdx.x * 128;
  const int r0 = blockIdx.y * 64;
  {
    float4* zt4 = (float4*)&zt[0][0];
    const float4* zm4 = (const float4*)(zmatch + (size_t)r0 * 128);
    for (int e = t; e < 2048; e += TPB) zt4[e] = zm4[e];
  }
  __syncthreads();
  const int cg = (t & 31) * 4;
  const int rg = t >> 5;
  float acc[8][4] = {};
  for (int j = 0; j < 128; j += 4) {
    float4 wv[4];
#pragma unroll
    for (int c = 0; c < 4; ++c) {
      int col = c0 + cg + c;
      wv[c] = (col < 3136) ? *(const float4*)(fcw + (size_t)col * 128 + j)
                           : make_float4(0.f, 0.f, 0.f, 0.f);
    }
#pragma unroll
    for (int k = 0; k < 8; ++k) {
      float4 zv = *(const float4*)&zt[rg * 8 + k][j];
#pragma unroll
      for (int c = 0; c < 4; ++c)
        acc[k][c] += wv[c].x * zv.x + wv[c].y * zv.y + wv[c].z * zv.z + wv[c].w * zv.w;
    }
  }
#pragma unroll
  for (int k = 0; k < 8; ++k) {
    int row = r0 + rg * 8 + k;
#pragma unroll
    for (int c = 0; c < 4; ++c) {
      int col = c0 + cg + c;
      if (col < 3136) d0ws[(size_t)row * 3136 + col] = acc[k][c] + fcb[col];
    }
  }
}

// ---------------------------------------------------------------------------
// Kernel 5: fused decoder v2 (unchanged)
// ---------------------------------------------------------------------------
__global__ __launch_bounds__(256) void decoder_kernel(
    const float* __restrict__ d0g, const float* __restrict__ w1,
    const float* __restrict__ b1, const float* __restrict__ w2,
    const float* __restrict__ b2, const float* __restrict__ w3,
    const float* __restrict__ b3, const float* __restrict__ w4,
    const float* __restrict__ b4, float* __restrict__ out) {
  __shared__ float Buf1[3136];
  __shared__ float Buf2[8192];

  const int b = blockIdx.x;
  const int t = threadIdx.x;
  const int lane = t & 63;
  const int ph = __builtin_amdgcn_readfirstlane(t >> 6);
  const int pa = ph >> 1, pb = ph & 1;

  for (int e = t; e < 3136; e += TPB) Buf1[e] = d0g[(size_t)b * 3136 + e];
  for (int e = t; e < 8192; e += TPB) Buf2[e] = 0.f;
  __syncthreads();

  {
    const int i = lane / 7, j = lane % 7;
    const int p = 2 * i + pa, q = 2 * j + pb;
    int ih[2], iw[2];
    float mh[2], mw[2];
#pragma unroll
    for (int s = 0; s < 2; ++s) {
      int v = i + pa + s - 1;
      mh[s] = (v >= 0 && v <= 6) ? 1.f : 0.f;
      ih[s] = v < 0 ? 0 : (v > 6 ? 6 : v);
      int u = j + pb + s - 1;
      mw[s] = (u >= 0 && u <= 6) ? 1.f : 0.f;
      iw[s] = u < 0 ? 0 : (u > 6 ? 6 : u);
    }
    const float m00 = mh[0] * mw[0], m01 = mh[0] * mw[1];
    const float m10 = mh[1] * mw[0], m11 = mh[1] * mw[1];
    const int tb = pa * 4 + pb;
    const float* wA = w1 + (size_t)tb * 2048;
    const float* wB = w1 + (size_t)(tb + 2) * 2048;
    const float* wC = w1 + (size_t)(tb + 8) * 2048;
    const float* wD = w1 + (size_t)(tb + 10) * 2048;
#pragma unroll 1
    for (int half = 0; half < 2; ++half) {
      const int o0 = half * 16;
      float acc[16];
#pragma unroll
      for (int oo = 0; oo < 16; ++oo) acc[oo] = b1[o0 + oo];
#pragma unroll 2
      for (int c = 0; c < 64; ++c) {
        const float a00 = Buf1[c * 49 + ih[0] * 7 + iw[0]] * m00;
        const float a01 = Buf1[c * 49 + ih[0] * 7 + iw[1]] * m01;
        const float a10 = Buf1[c * 49 + ih[1] * 7 + iw[0]] * m10;
        const float a11 = Buf1[c * 49 + ih[1] * 7 + iw[1]] * m11;
        const int wb = c * 32 + o0;
#pragma unroll
        for (int oo = 0; oo < 16; ++oo)
          acc[oo] += a00 * wA[wb + oo] + a01 * wB[wb + oo] +
                     a10 * wC[wb + oo] + a11 * wD[wb + oo];
      }
      if (lane < 49) {
        const int widx = (p + 1) * 16 + (q + 1);
#pragma unroll
        for (int oo = 0; oo < 16; ++oo)
          Buf2[(o0 + oo) * 256 + widx] = fmaxf(acc[oo], 0.f);
      }
    }
  }
  __syncthreads();

  {
    const int oq = __builtin_amdgcn_readfirstlane((t >> 6) * 4);
    const int pc2 = lane & 15, prl = lane >> 4;
    const int cpc = pc2 < 14 ? pc2 : 13;
    float acc[4][4] = {};
#pragma unroll 1
    for (int c = 0; c < 32; ++c) {
      float wr[4][9];
#pragma unroll
      for (int oo = 0; oo < 4; ++oo)
#pragma unroll
        for (int u = 0; u < 9; ++u)
          wr[oo][u] = w2[((oq + oo) * 32 + c) * 9 + u];
#pragma unroll
      for (int k = 0; k < 4; ++k) {
        int row = k * 4 + prl;
        int crow = row < 14 ? row : 13;
        const float* hp = &Buf2[c * 256 + crow * 16 + cpc];
        float hv[9];
#pragma unroll
        for (int di = 0; di < 3; ++di)
#pragma unroll
          for (int dj = 0; dj < 3; ++dj) hv[di * 3 + dj] = hp[di * 16 + dj];
#pragma unroll
        for (int oo = 0; oo < 4; ++oo) {
          float s = acc[oo][k];
#pragma unroll
          for (int u = 0; u < 9; ++u) s += hv[u] * wr[oo][u];
          acc[oo][k] = s;
        }
      }
    }
    if (pc2 < 14) {
#pragma unroll
      for (int k = 0; k < 4; ++k) {
        int row = k * 4 + prl;
        if (row < 14) {
#pragma unroll
          for (int oo = 0; oo < 4; ++oo)
            Buf1[(oq + oo) * 196 + row * 14 + pc2] =
                fmaxf(acc[oo][k] + b2[oq + oo], 0.f);
        }
      }
    }
  }
  __syncthreads();
  for (int e = t; e < 7200; e += TPB) Buf2[e] = 0.f;
  __syncthreads();

  {
    const int tb = pa * 4 + pb;
    const float* wA = w3 + (size_t)tb * 128;
    const float* wB = w3 + (size_t)(tb + 2) * 128;
    const float* wC = w3 + (size_t)(tb + 8) * 128;
    const float* wD = w3 + (size_t)(tb + 10) * 128;
#pragma unroll 1
    for (int k = 0; k < 4; ++k) {
      const int px = lane + 64 * k;
      const int cpx = px < 196 ? px : 195;
      const int i = cpx / 14, j = cpx % 14;
      int ih[2], iw[2];
      float mh[2], mw[2];
#pragma unroll
      for (int s = 0; s < 2; ++s) {
        int v = i + pa + s - 1;
        mh[s] = (v >= 0 && v <= 13) ? 1.f : 0.f;
        ih[s] = v < 0 ? 0 : (v > 13 ? 13 : v);
        int u = j + pb + s - 1;
        mw[s] = (u >= 0 && u <= 13) ? 1.f : 0.f;
        iw[s] = u < 0 ? 0 : (u > 13 ? 13 : u);
      }
      const float m00 = mh[0] * mw[0], m01 = mh[0] * mw[1];
      const float m10 = mh[1] * mw[0], m11 = mh[1] * mw[1];
      float acc[8];
#pragma unroll
      for (int oo = 0; oo < 8; ++oo) acc[oo] = b3[oo];
#pragma unroll 2
      for (int c = 0; c < 16; ++c) {
        const float a00 = Buf1[c * 196 + ih[0] * 14 + iw[0]] * m00;
        const float a01 = Buf1[c * 196 + ih[0] * 14 + iw[1]] * m01;
        const float a10 = Buf1[c * 196 + ih[1] * 14 + iw[0]] * m10;
        const float a11 = Buf1[c * 196 + ih[1] * 14 + iw[1]] * m11;
        const int wb = c * 8;
#pragma unroll
        for (int oo = 0; oo < 8; ++oo)
          acc[oo] += a00 * wA[wb + oo] + a01 * wB[wb + oo] +
                     a10 * wC[wb + oo] + a11 * wD[wb + oo];
      }
      if (px < 196) {
        const int p = 2 * i + pa, q = 2 * j + pb;
        const int widx = (p + 1) * 30 + (q + 1);
#pragma unroll
        for (int oo = 0; oo < 8; ++oo)
          Buf2[oo * 900 + widx] = fmaxf(acc[oo], 0.f);
      }
    }
  }
  __syncthreads();

  for (int e = t; e < 784; e += TPB) {
    int p = e / 28, q = e - p * 28;
    float a = b4[0];
#pragma unroll
    for (int c = 0; c < 8; ++c) {
      const float* bp = &Buf2[c * 900 + p * 30 + q];
#pragma unroll
      for (int di = 0; di < 3; ++di)
#pragma unroll
        for (int dj = 0; dj < 3; ++dj)
          a += bp[di * 30 + dj] * w4[c * 9 + di * 3 + dj];
    }
    out[(size_t)b * 784 + e] = a;
  }
}

// ---------------------------------------------------------------------------
extern "C" void kernel_launch(void* const* d_in, const int* in_sizes, int n_in,
                              void* d_out, int out_size, void* d_ws,
                              size_t ws_size, hipStream_t stream) {
  const float* x      = (const float*)d_in[0];
  const float* ce_w1  = (const float*)d_in[1];
  const float* ce_b1  = (const float*)d_in[2];
  const float* ce_w2  = (const float*)d_in[3];
  const float* ce_b2  = (const float*)d_in[4];
  const float* ce_fcw = (const float*)d_in[5];
  const float* ce_fcb = (const float*)d_in[6];
  const float* ge_w1  = (const float*)d_in[7];
  const float* ge_b1  = (const float*)d_in[8];
  const float* ge_w2  = (const float*)d_in[9];
  const float* ge_b2  = (const float*)d_in[10];
  const float* ge_fcw = (const float*)d_in[11];
  const float* ge_fcb = (const float*)d_in[12];
  const float* memg   = (const float*)d_in[13];
  const float* dfcw   = (const float*)d_in[14];
  const float* dfcb   = (const float*)d_in[15];
  const float* d_w1   = (const float*)d_in[16];
  const float* d_b1   = (const float*)d_in[17];
  const float* d_w2   = (const float*)d_in[18];
  const float* d_b2   = (const float*)d_in[19];
  const float* d_w3   = (const float*)d_in[20];
  const float* d_b3   = (const float*)d_in[21];
  const float* d_w4   = (const float*)d_in[22];
  const float* d_b4   = (const float*)d_in[23];
  float* outp = (float*)d_out;

  // ws layout (floats): z[262144] | zmatch[262144] | invn[8192] |
  // frags[36864] | d0ws[2048*3136].
  // topv/topi (2048*40 each) live INSIDE the d0ws region (disjoint lifetime:
  // written by match_part, consumed by match_merge, both before decfc).
  float* ws     = (float*)d_ws;
  float* z      = ws;
  float* zmatch = ws + 262144;
  float* invn   = ws + 524288;
  float* frags  = ws + 532480;
  float* d0ws   = ws + 532480 + 36864;
  float* topvw  = d0ws;
  int*   topiw  = (int*)(d0ws + 81920);

  prep_bfrags<<<144, 64, 0, stream>>>(ce_w2, ge_w2, frags);
  norm_kernel<<<2048, TPB, 0, stream>>>(memg, invn);
  encoders_fused<<<4096, TPB, 0, stream>>>(x, ce_w1, ce_b1, ce_b2, ce_fcw,
                                           ce_fcb, ge_w1, ge_b1, ge_b2, ge_fcw,
                                           ge_fcb, frags, z);
  match_part<<<dim3(256, 4), TPB, 0, stream>>>(z, memg, invn, topvw, topiw);
  match_merge<<<256, TPB, 0, stream>>>(topvw, topiw, memg, zmatch);
  decfc_kernel<<<dim3(25, 32), TPB, 0, stream>>>(zmatch, dfcw, dfcb, d0ws);
  decoder_kernel<<<2048, TPB, 0, stream>>>(d0ws, d_w1, d_b1, d_w2, d_b2, d_w3,
                                           d_b3, d_w4, d_b4, outp);
}

// Round 5
// 932.659 us; speedup vs baseline: 3.1585x; 1.1323x over previous
//
#include <hip/hip_runtime.h>
#include <cfloat>
#include <cmath>

#define TPB 256

typedef _Float16 half8 __attribute__((ext_vector_type(8)));
typedef float floatx16 __attribute__((ext_vector_type(16)));

__device__ __forceinline__ float wave_reduce_sum(float v) {
#pragma unroll
  for (int off = 32; off > 0; off >>= 1) v += __shfl_xor(v, off, 64);
  return v;
}

// ---------------------------------------------------------------------------
// Kernel 0: build conv2 B-fragments (2-part f16 split) for both encoders.
// frag value B[k][n] = w2[n][c][tap], c = half*16 + k, k = kg*8+j.
// Storage: [enc][fragidx = ks*4+part*2+nt][lane][16B], lane = kg*32+n32.
// ---------------------------------------------------------------------------
__global__ __launch_bounds__(64) void prep_bfrags(
    const float* __restrict__ ce_w2, const float* __restrict__ ge_w2,
    float* __restrict__ frags) {
  const int blk = blockIdx.x;  // 144 = 2 enc x 72 frags
  const int enc = blk / 72;
  const int frag = blk % 72;
  const int ks = frag >> 2, part = (frag >> 1) & 1, nt = frag & 1;
  const int tap = ks >> 1, half = ks & 1;
  const int lane = threadIdx.x;
  const float* w2 = enc ? ge_w2 : ce_w2;
  const int n = nt * 32 + (lane & 31);
  const int cb = half * 16 + (lane >> 5) * 8;
  half8 out;
#pragma unroll
  for (int j = 0; j < 8; ++j) {
    float v = w2[(n * 32 + cb + j) * 9 + tap];
    _Float16 h = (_Float16)v;
    out[j] = (part == 0) ? h : (_Float16)((v - (float)h) * 4096.f);
  }
  *(half8*)((char*)frags + ((size_t)blk * 64 + lane) * 16) = out;
}

// ---------------------------------------------------------------------------
// Kernel 1: memory row inverse norms
// ---------------------------------------------------------------------------
__global__ __launch_bounds__(256) void norm_kernel(
    const float* __restrict__ memg, float* __restrict__ invn) {
  const int wv = threadIdx.x >> 6, lane = threadIdx.x & 63;
  const int row = blockIdx.x * 4 + wv;
  const float* r = memg + (size_t)row * 128;
  float a = r[lane], b = r[lane + 64];
  float s = wave_reduce_sum(a * a + b * b);
  if (lane == 0) invn[row] = 1.f / fmaxf(sqrtf(s), 1e-12f);
}

// ---------------------------------------------------------------------------
// Kernel 2: MFMA encoder body. h1 stored [part][ch-group][pixel] (16B/entry)
// -> conflict-free lane-contiguous ds_read_b128 / ds_write_b128.
// B-fragments read from GLOBAL (coalesced, L2-hot) -> LDS 67 KB, 2 blocks/CU.
// conv1 writes halo zeros directly (no zeroing pass).
// conv2 GEMM via v_mfma_f32_32x32x16_f16: D = Ah*Bh + 2^-12(Ah*Bl' + Al'*Bh).
// ---------------------------------------------------------------------------
template <int S, bool CENTER>
__device__ __forceinline__ void encoder_body(
    char* smem, const float* __restrict__ x, const float* __restrict__ w1,
    const float* __restrict__ b1, const float* __restrict__ b2,
    const float* __restrict__ fcw, const float* __restrict__ fcb,
    const float* __restrict__ bfrag, float* __restrict__ zout, int zoff,
    int b) {
  constexpr int SP = S + 2;              // padded width
  constexpr int NB = S / 14;             // bands of 14 output rows
  constexpr int ROWS = 16;               // band rows incl. halo
  constexpr int NPIX = ROWS * SP;        // 480 / 256
  constexpr int GSTB = NPIX * 16;        // ch-group stride bytes
  constexpr int PSTB = 4 * GSTB;         // part stride bytes
  constexpr int LIMIT = 14 * S;          // valid px per band
  constexpr int MTB = (LIMIT + 31) / 32; // M-tiles per band (13 / 7)
  constexpr int NBLK = (MTB + 1) / 2;    // M-blocks per band (7 / 4)

  char* h1s = smem;                      // 2*PSTB bytes
  float* xs = (float*)(smem + 2 * PSTB);
  float* w1s = xs + SP * SP;
  float(*featp)[64] = (float(*)[64])(w1s + 288);

  const int t = threadIdx.x;
  const int lane = t & 63;
  const int wv = t >> 6;

  for (int e = t; e < SP * SP; e += TPB) xs[e] = 0.f;
  for (int e = t; e < 288; e += TPB) w1s[e] = w1[e];
  __syncthreads();
  const float* xb = x + (size_t)b * 784 + (CENTER ? (7 * 28 + 7) : 0);
  for (int e = t; e < S * S; e += TPB) {
    int i = e / S, j = e - i * S;
    xs[(i + 1) * SP + (j + 1)] = xb[i * 28 + j];
  }

  float sp0 = 0.f, sp1 = 0.f;
  const float bias0 = b2[lane & 31];
  const float bias1 = b2[32 + (lane & 31)];
  const int gOff = (lane >> 5) * GSTB;          // kg -> ch-group byte offset
  const char* bgbase = (const char*)bfrag + lane * 16;

  for (int band = 0; band < NB; ++band) {
    const int b0 = band * 14;
    __syncthreads();  // xs ready / h1 consumed by previous band
    // conv1: fill h1 band [part][g][lr*SP+cw], zeros for halo positions
    for (int e = t; e < 4 * NPIX; e += TPB) {
      int g = e / NPIX;
      int pix = e - g * NPIX;
      int lr = pix / SP;
      int cw = pix - lr * SP;
      int gr = b0 - 1 + lr;
      int ebase = g * GSTB + pix * 16;
      half8 hi8 = {}, lo8 = {};
      if (gr >= 0 && gr < S && cw >= 1 && cw <= S) {
        float xv[9];
#pragma unroll
        for (int di = 0; di < 3; ++di)
#pragma unroll
          for (int dj = 0; dj < 3; ++dj)
            xv[di * 3 + dj] = xs[(gr + di) * SP + (cw - 1 + dj)];
#pragma unroll
        for (int u = 0; u < 8; ++u) {
          int ch = g * 8 + u;
          float a = b1[ch];
#pragma unroll
          for (int v = 0; v < 9; ++v) a += xv[v] * w1s[ch * 9 + v];
          a = fmaxf(a, 0.f);
          _Float16 h = (_Float16)a;
          hi8[u] = h;
          lo8[u] = (_Float16)((a - (float)h) * 4096.f);
        }
      }
      *(half8*)(h1s + ebase) = hi8;
      *(half8*)(h1s + PSTB + ebase) = lo8;
    }
    __syncthreads();
    // conv2 MFMA: wave-strided M-blocks of 2 tiles
    for (int mblk = wv; mblk < NBLK; mblk += 4) {
      const int Mt0 = mblk * 2;
      floatx16 acc[2][2][2] = {};  // [Mtile][Ntile][term hi/lo]
      int pixB[2];
#pragma unroll
      for (int im = 0; im < 2; ++im) {
        int px = (Mt0 + im) * 32 + (lane & 31);
        px = px < LIMIT ? px : LIMIT - 1;
        int r = px / S;
        int cc = px - r * S;
        pixB[im] = (r * SP + cc) * 16;
      }
#pragma unroll 3
      for (int tap = 0; tap < 9; ++tap) {
        const int di = tap / 3, dj = tap - di * 3;
        const int offT = (di * SP + dj) * 16;
#pragma unroll
        for (int half = 0; half < 2; ++half) {
          const int ks = tap * 2 + half;
          const char* bp = bgbase + ks * 4096;
          half8 bh0 = *(const half8*)(bp);
          half8 bh1 = *(const half8*)(bp + 1024);
          half8 bl0 = *(const half8*)(bp + 2048);
          half8 bl1 = *(const half8*)(bp + 3072);
          const int offA = offT + gOff + half * (2 * GSTB);
#pragma unroll
          for (int im = 0; im < 2; ++im) {
            half8 ah = *(const half8*)(h1s + pixB[im] + offA);
            half8 al = *(const half8*)(h1s + PSTB + pixB[im] + offA);
            acc[im][0][0] = __builtin_amdgcn_mfma_f32_32x32x16_f16(
                ah, bh0, acc[im][0][0], 0, 0, 0);
            acc[im][1][0] = __builtin_amdgcn_mfma_f32_32x32x16_f16(
                ah, bh1, acc[im][1][0], 0, 0, 0);
            acc[im][0][1] = __builtin_amdgcn_mfma_f32_32x32x16_f16(
                ah, bl0, acc[im][0][1], 0, 0, 0);
            acc[im][0][1] = __builtin_amdgcn_mfma_f32_32x32x16_f16(
                al, bh0, acc[im][0][1], 0, 0, 0);
            acc[im][1][1] = __builtin_amdgcn_mfma_f32_32x32x16_f16(
                ah, bl1, acc[im][1][1], 0, 0, 0);
            acc[im][1][1] = __builtin_amdgcn_mfma_f32_32x32x16_f16(
                al, bh1, acc[im][1][1], 0, 0, 0);
          }
        }
      }
      // pool: feat[n] += relu(D + bias), D = acc_hi + acc_lo * 2^-12
#pragma unroll
      for (int im = 0; im < 2; ++im)
#pragma unroll
        for (int reg = 0; reg < 16; ++reg) {
          int row = (reg & 3) + 8 * (reg >> 2) + 4 * (lane >> 5);
          int p = (Mt0 + im) * 32 + row;
          if (p < LIMIT) {
            float v0 =
                acc[im][0][0][reg] + acc[im][0][1][reg] * (1.f / 4096.f) + bias0;
            float v1 =
                acc[im][1][0][reg] + acc[im][1][1][reg] * (1.f / 4096.f) + bias1;
            sp0 += fmaxf(v0, 0.f);
            sp1 += fmaxf(v1, 0.f);
          }
        }
    }
  }
  sp0 += __shfl_xor(sp0, 32);
  sp1 += __shfl_xor(sp1, 32);
  if (lane < 32) {
    featp[wv][lane] = sp0;
    featp[wv][32 + lane] = sp1;
  }
  __syncthreads();
  if (t < 64)
    featp[0][t] = (featp[0][t] + featp[1][t] + featp[2][t] + featp[3][t]) *
                  (1.f / (S * S));
  __syncthreads();
  if (t < 64) {
    float s = 0.f;
#pragma unroll
    for (int i = 0; i < 64; ++i) s += featp[0][i] * fcw[t * 64 + i];
    zout[(size_t)b * 128 + zoff + t] = s + fcb[t];
  }
}

// Fused launch: blocks 0..2047 = global encoder, 2048..4095 = center encoder.
// LDS: 2*PSTB(S=28)=61440 + xs 3600 + w1s 1152 + featp 1024 = 67216 B.
__global__ __launch_bounds__(256, 2) void encoders_fused(
    const float* __restrict__ x, const float* __restrict__ ce_w1,
    const float* __restrict__ ce_b1, const float* __restrict__ ce_b2,
    const float* __restrict__ ce_fcw, const float* __restrict__ ce_fcb,
    const float* __restrict__ ge_w1, const float* __restrict__ ge_b1,
    const float* __restrict__ ge_b2, const float* __restrict__ ge_fcw,
    const float* __restrict__ ge_fcb, const float* __restrict__ frags,
    float* __restrict__ z) {
  __shared__ __align__(16) char smem[67216];
  if (blockIdx.x < 2048)
    encoder_body<28, false>(smem, x, ge_w1, ge_b1, ge_b2, ge_fcw, ge_fcb,
                            frags + 18432, z, 64, blockIdx.x);
  else
    encoder_body<14, true>(smem, x, ce_w1, ce_b1, ce_b2, ce_fcw, ce_fcb, frags,
                           z, 0, blockIdx.x - 2048);
}

// ---------------------------------------------------------------------------
// Kernel 3a: partial match. Grid (256 z-groups, 4 mem-quarters).
// ---------------------------------------------------------------------------
__global__ __launch_bounds__(256) void match_part(
    const float* __restrict__ z, const float* __restrict__ memg,
    const float* __restrict__ invn, float* __restrict__ topvw,
    int* __restrict__ topiw) {
  __shared__ __align__(16) float zs[8][128];
  __shared__ float qv[8][512];
  __shared__ int qi[8][512];
  __shared__ int qn[8];
  __shared__ float rowmin[8];

  const int t = threadIdx.x;
  const int rowbase = blockIdx.x * 8;
  const int mbase = blockIdx.y * 2048;

  for (int e = t; e < 8 * 128; e += TPB) {
    int r = e >> 7, j = e & 127;
    zs[r][j] = z[(size_t)(rowbase + r) * 128 + j];
  }
  if (t < 8) { qn[t] = 0; rowmin[t] = -FLT_MAX; }
  __syncthreads();
  {
    int wv = t >> 6, lane = t & 63;
#pragma unroll
    for (int h = 0; h < 2; ++h) {
      int r = wv + h * 4;
      float a = zs[r][lane], b = zs[r][lane + 64];
      float s = wave_reduce_sum(a * a + b * b);
      float inv = 1.f / fmaxf(sqrtf(s), 1e-12f);
      zs[r][lane] = a * inv;
      zs[r][lane + 64] = b * inv;
    }
  }
  __syncthreads();

  float av[10];
  int ai[10];
#pragma unroll
  for (int i = 0; i < 10; ++i) { av[i] = -FLT_MAX; ai[i] = 0; }

  for (int mt = 0; mt < 4; ++mt) {
    int m0 = mbase + mt * 512 + t;
    float acc0[8] = {}, acc1[8] = {};
    const float4* mr0 = (const float4*)(memg + (size_t)m0 * 128);
    const float4* mr1 = (const float4*)(memg + (size_t)(m0 + 256) * 128);
#pragma unroll 4
    for (int jq = 0; jq < 32; ++jq) {
      float4 a0 = mr0[jq], a1 = mr1[jq];
#pragma unroll
      for (int r = 0; r < 8; ++r) {
        float4 zv = ((const float4*)zs[r])[jq];
        acc0[r] += a0.x * zv.x + a0.y * zv.y + a0.z * zv.z + a0.w * zv.w;
        acc1[r] += a1.x * zv.x + a1.y * zv.y + a1.z * zv.z + a1.w * zv.w;
      }
    }
    float i0 = invn[m0], i1 = invn[m0 + 256];
#pragma unroll
    for (int r = 0; r < 8; ++r) {
      float rm = rowmin[r];
      float v0 = acc0[r] * i0;
      if (v0 > rm) {
        int k = atomicAdd(&qn[r], 1);
        qv[r][k] = v0; qi[r][k] = m0;
      }
      float v1 = acc1[r] * i1;
      if (v1 > rm) {
        int k = atomicAdd(&qn[r], 1);
        qv[r][k] = v1; qi[r][k] = m0 + 256;
      }
    }
    __syncthreads();
    if (t < 8) {
      int n = qn[t];
      for (int k = 0; k < n; ++k) {
        float v = qv[t][k];
        int m = qi[t][k];
        if (v > av[9]) {
#pragma unroll
          for (int i = 0; i < 10; ++i) {
            if (v > av[i]) {
              float tv = av[i]; av[i] = v; v = tv;
              int ti = ai[i]; ai[i] = m; m = ti;
            }
          }
        }
      }
      qn[t] = 0;
      rowmin[t] = av[9];
    }
    __syncthreads();
  }

  if (t < 8) {
    const size_t base = (size_t)(rowbase + t) * 40 + blockIdx.y * 10;
#pragma unroll
    for (int k = 0; k < 10; ++k) {
      topvw[base + k] = av[k];
      topiw[base + k] = ai[k];
    }
  }
}

// ---------------------------------------------------------------------------
// Kernel 3b: merge 4x10 candidates -> exact top-10 -> softmax -> blend.
// ---------------------------------------------------------------------------
__global__ __launch_bounds__(256) void match_merge(
    const float* __restrict__ topvw, const int* __restrict__ topiw,
    const float* __restrict__ memg, float* __restrict__ zmatch) {
  __shared__ float topw[8][10];
  __shared__ int topidx[8][10];
  const int t = threadIdx.x;
  const int rowbase = blockIdx.x * 8;

  if (t < 8) {
    float av[10];
    int ai[10];
#pragma unroll
    for (int i = 0; i < 10; ++i) { av[i] = -FLT_MAX; ai[i] = 0; }
    const size_t base = (size_t)(rowbase + t) * 40;
    for (int c = 0; c < 40; ++c) {
      float v = topvw[base + c];
      int m = topiw[base + c];
      if (v > av[9]) {
#pragma unroll
        for (int i = 0; i < 10; ++i) {
          if (v > av[i]) {
            float tv = av[i]; av[i] = v; v = tv;
            int ti = ai[i]; ai[i] = m; m = ti;
          }
        }
      }
    }
    float e_[10], s = 0.f;
#pragma unroll
    for (int k = 0; k < 10; ++k) { e_[k] = expf(av[k]); s += e_[k]; }
    float inv = 1.f / s;
#pragma unroll
    for (int k = 0; k < 10; ++k) { topw[t][k] = e_[k] * inv; topidx[t][k] = ai[k]; }
  }
  __syncthreads();
  for (int e = t; e < 8 * 128; e += TPB) {
    int r = e >> 7, d = e & 127;
    float o = 0.f;
#pragma unroll
    for (int k = 0; k < 10; ++k)
      o += topw[r][k] * memg[(size_t)topidx[r][k] * 128 + d];
    zmatch[(size_t)(rowbase + r) * 128 + d] = o;
  }
}

// ---------------------------------------------------------------------------
// Kernel 4: decoder FC GEMM (unchanged)
// ---------------------------------------------------------------------------
__global__ __launch_bounds__(256) void decfc_kernel(
    const float* __restrict__ zmatch, const float* __restrict__ fcw,
    const float* __restrict__ fcb, float* __restrict__ d0ws) {
  __shared__ __align__(16) float zt[64][128];
  const int t = threadIdx.x;
  const int c0 = blockIdx.x * 128;
  const int r0 = blockIdx.y * 64;
  {
    float4* zt4 = (float4*)&zt[0][0];
    const float4* zm4 = (const float4*)(zmatch + (size_t)r0 * 128);
    for (int e = t; e < 2048; e += TPB) zt4[e] = zm4[e];
  }
  __syncthreads();
  const int cg = (t & 31) * 4;
  const int rg = t >> 5;
  float acc[8][4] = {};
  for (int j = 0; j < 128; j += 4) {
    float4 wv[4];
#pragma unroll
    for (int c = 0; c < 4; ++c) {
      int col = c0 + cg + c;
      wv[c] = (col < 3136) ? *(const float4*)(fcw + (size_t)col * 128 + j)
                           : make_float4(0.f, 0.f, 0.f, 0.f);
    }
#pragma unroll
    for (int k = 0; k < 8; ++k) {
      float4 zv = *(const float4*)&zt[rg * 8 + k][j];
#pragma unroll
      for (int c = 0; c < 4; ++c)
        acc[k][c] += wv[c].x * zv.x + wv[c].y * zv.y + wv[c].z * zv.z + wv[c].w * zv.w;
    }
  }
#pragma unroll
  for (int k = 0; k < 8; ++k) {
    int row = r0 + rg * 8 + k;
#pragma unroll
    for (int c = 0; c < 4; ++c) {
      int col = c0 + cg + c;
      if (col < 3136) d0ws[(size_t)row * 3136 + col] = acc[k][c] + fcb[col];
    }
  }
}

// ---------------------------------------------------------------------------
// Kernel 5: fused decoder v2 (unchanged)
// ---------------------------------------------------------------------------
__global__ __launch_bounds__(256) void decoder_kernel(
    const float* __restrict__ d0g, const float* __restrict__ w1,
    const float* __restrict__ b1, const float* __restrict__ w2,
    const float* __restrict__ b2, const float* __restrict__ w3,
    const float* __restrict__ b3, const float* __restrict__ w4,
    const float* __restrict__ b4, float* __restrict__ out) {
  __shared__ float Buf1[3136];
  __shared__ float Buf2[8192];

  const int b = blockIdx.x;
  const int t = threadIdx.x;
  const int lane = t & 63;
  const int ph = __builtin_amdgcn_readfirstlane(t >> 6);
  const int pa = ph >> 1, pb = ph & 1;

  for (int e = t; e < 3136; e += TPB) Buf1[e] = d0g[(size_t)b * 3136 + e];
  for (int e = t; e < 8192; e += TPB) Buf2[e] = 0.f;
  __syncthreads();

  {
    const int i = lane / 7, j = lane % 7;
    const int p = 2 * i + pa, q = 2 * j + pb;
    int ih[2], iw[2];
    float mh[2], mw[2];
#pragma unroll
    for (int s = 0; s < 2; ++s) {
      int v = i + pa + s - 1;
      mh[s] = (v >= 0 && v <= 6) ? 1.f : 0.f;
      ih[s] = v < 0 ? 0 : (v > 6 ? 6 : v);
      int u = j + pb + s - 1;
      mw[s] = (u >= 0 && u <= 6) ? 1.f : 0.f;
      iw[s] = u < 0 ? 0 : (u > 6 ? 6 : u);
    }
    const float m00 = mh[0] * mw[0], m01 = mh[0] * mw[1];
    const float m10 = mh[1] * mw[0], m11 = mh[1] * mw[1];
    const int tb = pa * 4 + pb;
    const float* wA = w1 + (size_t)tb * 2048;
    const float* wB = w1 + (size_t)(tb + 2) * 2048;
    const float* wC = w1 + (size_t)(tb + 8) * 2048;
    const float* wD = w1 + (size_t)(tb + 10) * 2048;
#pragma unroll 1
    for (int half = 0; half < 2; ++half) {
      const int o0 = half * 16;
      float acc[16];
#pragma unroll
      for (int oo = 0; oo < 16; ++oo) acc[oo] = b1[o0 + oo];
#pragma unroll 2
      for (int c = 0; c < 64; ++c) {
        const float a00 = Buf1[c * 49 + ih[0] * 7 + iw[0]] * m00;
        const float a01 = Buf1[c * 49 + ih[0] * 7 + iw[1]] * m01;
        const float a10 = Buf1[c * 49 + ih[1] * 7 + iw[0]] * m10;
        const float a11 = Buf1[c * 49 + ih[1] * 7 + iw[1]] * m11;
        const int wb = c * 32 + o0;
#pragma unroll
        for (int oo = 0; oo < 16; ++oo)
          acc[oo] += a00 * wA[wb + oo] + a01 * wB[wb + oo] +
                     a10 * wC[wb + oo] + a11 * wD[wb + oo];
      }
      if (lane < 49) {
        const int widx = (p + 1) * 16 + (q + 1);
#pragma unroll
        for (int oo = 0; oo < 16; ++oo)
          Buf2[(o0 + oo) * 256 + widx] = fmaxf(acc[oo], 0.f);
      }
    }
  }
  __syncthreads();

  {
    const int oq = __builtin_amdgcn_readfirstlane((t >> 6) * 4);
    const int pc2 = lane & 15, prl = lane >> 4;
    const int cpc = pc2 < 14 ? pc2 : 13;
    float acc[4][4] = {};
#pragma unroll 1
    for (int c = 0; c < 32; ++c) {
      float wr[4][9];
#pragma unroll
      for (int oo = 0; oo < 4; ++oo)
#pragma unroll
        for (int u = 0; u < 9; ++u)
          wr[oo][u] = w2[((oq + oo) * 32 + c) * 9 + u];
#pragma unroll
      for (int k = 0; k < 4; ++k) {
        int row = k * 4 + prl;
        int crow = row < 14 ? row : 13;
        const float* hp = &Buf2[c * 256 + crow * 16 + cpc];
        float hv[9];
#pragma unroll
        for (int di = 0; di < 3; ++di)
#pragma unroll
          for (int dj = 0; dj < 3; ++dj) hv[di * 3 + dj] = hp[di * 16 + dj];
#pragma unroll
        for (int oo = 0; oo < 4; ++oo) {
          float s = acc[oo][k];
#pragma unroll
          for (int u = 0; u < 9; ++u) s += hv[u] * wr[oo][u];
          acc[oo][k] = s;
        }
      }
    }
    if (pc2 < 14) {
#pragma unroll
      for (int k = 0; k < 4; ++k) {
        int row = k * 4 + prl;
        if (row < 14) {
#pragma unroll
          for (int oo = 0; oo < 4; ++oo)
            Buf1[(oq + oo) * 196 + row * 14 + pc2] =
                fmaxf(acc[oo][k] + b2[oq + oo], 0.f);
        }
      }
    }
  }
  __syncthreads();
  for (int e = t; e < 7200; e += TPB) Buf2[e] = 0.f;
  __syncthreads();

  {
    const int tb = pa * 4 + pb;
    const float* wA = w3 + (size_t)tb * 128;
    const float* wB = w3 + (size_t)(tb + 2) * 128;
    const float* wC = w3 + (size_t)(tb + 8) * 128;
    const float* wD = w3 + (size_t)(tb + 10) * 128;
#pragma unroll 1
    for (int k = 0; k < 4; ++k) {
      const int px = lane + 64 * k;
      const int cpx = px < 196 ? px : 195;
      const int i = cpx / 14, j = cpx % 14;
      int ih[2], iw[2];
      float mh[2], mw[2];
#pragma unroll
      for (int s = 0; s < 2; ++s) {
        int v = i + pa + s - 1;
        mh[s] = (v >= 0 && v <= 13) ? 1.f : 0.f;
        ih[s] = v < 0 ? 0 : (v > 13 ? 13 : v);
        int u = j + pb + s - 1;
        mw[s] = (u >= 0 && u <= 13) ? 1.f : 0.f;
        iw[s] = u < 0 ? 0 : (u > 13 ? 13 : u);
      }
      const float m00 = mh[0] * mw[0], m01 = mh[0] * mw[1];
      const float m10 = mh[1] * mw[0], m11 = mh[1] * mw[1];
      float acc[8];
#pragma unroll
      for (int oo = 0; oo < 8; ++oo) acc[oo] = b3[oo];
#pragma unroll 2
      for (int c = 0; c < 16; ++c) {
        const float a00 = Buf1[c * 196 + ih[0] * 14 + iw[0]] * m00;
        const float a01 = Buf1[c * 196 + ih[0] * 14 + iw[1]] * m01;
        const float a10 = Buf1[c * 196 + ih[1] * 14 + iw[0]] * m10;
        const float a11 = Buf1[c * 196 + ih[1] * 14 + iw[1]] * m11;
        const int wb = c * 8;
#pragma unroll
        for (int oo = 0; oo < 8; ++oo)
          acc[oo] += a00 * wA[wb + oo] + a01 * wB[wb + oo] +
                     a10 * wC[wb + oo] + a11 * wD[wb + oo];
      }
      if (px < 196) {
        const int p = 2 * i + pa, q = 2 * j + pb;
        const int widx = (p + 1) * 30 + (q + 1);
#pragma unroll
        for (int oo = 0; oo < 8; ++oo)
          Buf2[oo * 900 + widx] = fmaxf(acc[oo], 0.f);
      }
    }
  }
  __syncthreads();

  for (int e = t; e < 784; e += TPB) {
    int p = e / 28, q = e - p * 28;
    float a = b4[0];
#pragma unroll
    for (int c = 0; c < 8; ++c) {
      const float* bp = &Buf2[c * 900 + p * 30 + q];
#pragma unroll
      for (int di = 0; di < 3; ++di)
#pragma unroll
        for (int dj = 0; dj < 3; ++dj)
          a += bp[di * 30 + dj] * w4[c * 9 + di * 3 + dj];
    }
    out[(size_t)b * 784 + e] = a;
  }
}

// ---------------------------------------------------------------------------
extern "C" void kernel_launch(void* const* d_in, const int* in_sizes, int n_in,
                              void* d_out, int out_size, void* d_ws,
                              size_t ws_size, hipStream_t stream) {
  const float* x      = (const float*)d_in[0];
  const float* ce_w1  = (const float*)d_in[1];
  const float* ce_b1  = (const float*)d_in[2];
  const float* ce_w2  = (const float*)d_in[3];
  const float* ce_b2  = (const float*)d_in[4];
  const float* ce_fcw = (const float*)d_in[5];
  const float* ce_fcb = (const float*)d_in[6];
  const float* ge_w1  = (const float*)d_in[7];
  const float* ge_b1  = (const float*)d_in[8];
  const float* ge_w2  = (const float*)d_in[9];
  const float* ge_b2  = (const float*)d_in[10];
  const float* ge_fcw = (const float*)d_in[11];
  const float* ge_fcb = (const float*)d_in[12];
  const float* memg   = (const float*)d_in[13];
  const float* dfcw   = (const float*)d_in[14];
  const float* dfcb   = (const float*)d_in[15];
  const float* d_w1   = (const float*)d_in[16];
  const float* d_b1   = (const float*)d_in[17];
  const float* d_w2   = (const float*)d_in[18];
  const float* d_b2   = (const float*)d_in[19];
  const float* d_w3   = (const float*)d_in[20];
  const float* d_b3   = (const float*)d_in[21];
  const float* d_w4   = (const float*)d_in[22];
  const float* d_b4   = (const float*)d_in[23];
  float* outp = (float*)d_out;

  // ws layout (floats): z[262144] | zmatch[262144] | invn[8192] |
  // frags[36864] | d0ws[2048*3136].
  // topv/topi (2048*40 each) alias the d0ws region (disjoint lifetimes).
  float* ws     = (float*)d_ws;
  float* z      = ws;
  float* zmatch = ws + 262144;
  float* invn   = ws + 524288;
  float* frags  = ws + 532480;
  float* d0ws   = ws + 532480 + 36864;
  float* topvw  = d0ws;
  int*   topiw  = (int*)(d0ws + 81920);

  prep_bfrags<<<144, 64, 0, stream>>>(ce_w2, ge_w2, frags);
  norm_kernel<<<2048, TPB, 0, stream>>>(memg, invn);
  encoders_fused<<<4096, TPB, 0, stream>>>(x, ce_w1, ce_b1, ce_b2, ce_fcw,
                                           ce_fcb, ge_w1, ge_b1, ge_b2, ge_fcw,
                                           ge_fcb, frags, z);
  match_part<<<dim3(256, 4), TPB, 0, stream>>>(z, memg, invn, topvw, topiw);
  match_merge<<<256, TPB, 0, stream>>>(topvw, topiw, memg, zmatch);
  decfc_kernel<<<dim3(25, 32), TPB, 0, stream>>>(zmatch, dfcw, dfcb, d0ws);
  decoder_kernel<<<2048, TPB, 0, stream>>>(d0ws, d_w1, d_b1, d_w2, d_b2, d_w3,
                                           d_b3, d_w4, d_b4, outp);
}